// Round 9
// baseline (247.953 us; speedup 1.0000x reference)
//
#include <hip/hip_runtime.h>
#include <hip/hip_bf16.h>
#include <cstdint>

// Problem constants (fixed): B=4, S=2048, E=1024, H=16, HD=64
#define NB 4
#define NS 2048
#define NE 1024
#define NH 16

typedef __attribute__((ext_vector_type(8))) short bf16x8;   // 8 bf16 (4 VGPRs)
typedef __attribute__((ext_vector_type(4))) float f32x4;    // MFMA C/D

__device__ __forceinline__ unsigned short f2bf(float f) {
  unsigned u = __float_as_uint(f);
  u += 0x7fffu + ((u >> 16) & 1u);   // RNE
  return (unsigned short)(u >> 16);
}

// pack two fp32 -> bf16x2 in one b32: +0x8000 round (half-up) + v_perm
__device__ __forceinline__ unsigned pk2bf(float lo, float hi) {
  return __builtin_amdgcn_perm(__float_as_uint(hi) + 0x8000u,
                               __float_as_uint(lo) + 0x8000u, 0x07060302u);
}

__device__ __forceinline__ float exp2_fast(float x) {
#if __has_builtin(__builtin_amdgcn_exp2f)
  return __builtin_amdgcn_exp2f(x);
#else
  float r;
  asm("v_exp_f32 %0, %1" : "=v"(r) : "v"(x));
  return r;
#endif
}

// async global->LDS, 16B/lane. LDS dest = wave-uniform base + lane*16.
__device__ __forceinline__ void gl_lds16(const void* g, void* l) {
  __builtin_amdgcn_global_load_lds(
      (const __attribute__((address_space(1))) void*)g,
      (__attribute__((address_space(3))) void*)l, 16, 0, 0);
}

// ---------------- fused cast fp32 -> bf16 (x | qkv_w | out_w) ----------------
// Destinations are contiguous in ws in this exact order, so out[idx] works
// for all three ranges. Ranges in float4 units:
//   x:     [0, 2097152)          -> xb
//   qkv_w: [2097152, 2883584)    -> wqkv
//   out_w: [2883584, 3145728)    -> wo
// Grid = 3145728/256 = 12288 exact (no bounds check). R9: replaces 3 launches.
__global__ __launch_bounds__(256) void cast3_k(const float* __restrict__ x,
                                               const float* __restrict__ w1,
                                               const float* __restrict__ w2,
                                               unsigned short* __restrict__ out) {
  int idx = blockIdx.x * 256 + threadIdx.x;
  const float4* src;
  int local = idx;
  if (idx < 2097152) {
    src = (const float4*)x;
  } else if (idx < 2883584) {
    src = (const float4*)w1; local = idx - 2097152;
  } else {
    src = (const float4*)w2; local = idx - 2883584;
  }
  float4 v = src[local];
  ushort4 o;
  o.x = f2bf(v.x); o.y = f2bf(v.y); o.z = f2bf(v.z); o.w = f2bf(v.w);
  ((ushort4*)out)[idx] = o;
}

// ---------------- C = A[M,K] @ B[N,K]^T + bias ----------------
// 128x128 tile, 4 waves 2x2, 4x4 MFMA/wave, BK=64, global_load_lds staging.
// NO block swizzle (R5 post-mortem): with dim3(24,64), lin=24y+x and 24y%8==0
// so XCD = x%8 -> each XCD already owns 3 FIXED B-column-panels (768KB,
// L2-resident, reused across all 64 M-rows). Keep the natural mapping.
// R9 epilogue: Q/K/V category is wave-uniform per j (16-col windows never
// cross the 192-col head boundaries, both multiples of 16) -> hoist branch;
// V packed as ushort4 (r=0..3 -> 4 consecutive s for fixed d): 4x fewer V
// stores, 8B/lane write granularity (was 64 scalar 2B stores -> partial-line
// writes, WRITE_SIZE 67MB vs 50MB ideal).
template <int MODE>
__global__ __launch_bounds__(256, 2) void gemm_bt(
    const unsigned short* __restrict__ A,   // [M,K] bf16
    const unsigned short* __restrict__ Bm,  // [N,K] bf16
    const float* __restrict__ bias,         // [N] fp32
    void* __restrict__ Cv,                  // MODE0: fp32 [M,N]
    unsigned short* __restrict__ Qp,        // MODE1: [bh][s][64]
    unsigned short* __restrict__ Kp,        // MODE1: [bh][s][64]
    unsigned short* __restrict__ Vp,        // MODE1: [bh][d][s]
    int M, int N, int K) {
  __shared__ __align__(16) unsigned short As[128 * 64];
  __shared__ __align__(16) unsigned short Bs[128 * 64];
  const int tid = threadIdx.x;
  const int lane = tid & 63, wave = tid >> 6;
  const int m0 = blockIdx.y * 128, n0 = blockIdx.x * 128;
  const int wm = (wave >> 1) * 64, wn = (wave & 1) * 64;
  const int fr = lane & 15, fq = lane >> 4;

  f32x4 acc[4][4];
#pragma unroll
  for (int i = 0; i < 4; i++)
#pragma unroll
    for (int j = 0; j < 4; j++) acc[i][j] = (f32x4){0.f, 0.f, 0.f, 0.f};

  const int srow = lane >> 3;                   // 0..7 within 8-row chunk
  const int scol = ((lane & 7) ^ srow) * 8;     // swizzled global col (elems)

  for (int kt = 0; kt < K; kt += 64) {
    __syncthreads();
#pragma unroll
    for (int c = 0; c < 4; c++) {
      const int chunk = wave * 4 + c;           // 0..15, 8 rows each
      const int row = chunk * 8 + srow;
      gl_lds16(A + (size_t)(m0 + row) * K + kt + scol, As + chunk * 512);
      gl_lds16(Bm + (size_t)(n0 + row) * K + kt + scol, Bs + chunk * 512);
    }
    __syncthreads();
#pragma unroll
    for (int s = 0; s < 2; s++) {
      bf16x8 af[4], bf[4];
#pragma unroll
      for (int i = 0; i < 4; i++)
        af[i] = *(const bf16x8*)(As + (wm + i * 16 + fr) * 64 +
                                 (((s * 4 + fq) ^ (fr & 7)) * 8));
#pragma unroll
      for (int j = 0; j < 4; j++)
        bf[j] = *(const bf16x8*)(Bs + (wn + j * 16 + fr) * 64 +
                                 (((s * 4 + fq) ^ (fr & 7)) * 8));
#pragma unroll
      for (int i = 0; i < 4; i++)
#pragma unroll
        for (int j = 0; j < 4; j++)
          acc[i][j] = __builtin_amdgcn_mfma_f32_16x16x32_bf16(af[i], bf[j], acc[i][j], 0, 0, 0);
    }
  }

#pragma unroll
  for (int j = 0; j < 4; j++) {
    const int col = n0 + wn + j * 16 + fr;
    const float bval = bias[col];
    if (MODE == 0) {
#pragma unroll
      for (int i = 0; i < 4; i++)
#pragma unroll
        for (int r = 0; r < 4; r++) {
          const int row = m0 + wm + i * 16 + fq * 4 + r;
          ((float*)Cv)[(size_t)row * N + col] = acc[i][j][r] + bval;
        }
    } else {
      const int h = col / 192, rr = col - h * 192;
      if (rr < 64) {          // Q, pre-scaled into exp2 domain
#pragma unroll
        for (int i = 0; i < 4; i++)
#pragma unroll
          for (int r = 0; r < 4; r++) {
            const int row = m0 + wm + i * 16 + fq * 4 + r;
            const int b = row >> 11, s = row & 2047;
            Qp[((size_t)(b * 16 + h) * 2048 + s) * 64 + rr] =
                f2bf((acc[i][j][r] + bval) * 0.1803368802f);
          }
      } else if (rr < 128) {  // K
#pragma unroll
        for (int i = 0; i < 4; i++)
#pragma unroll
          for (int r = 0; r < 4; r++) {
            const int row = m0 + wm + i * 16 + fq * 4 + r;
            const int b = row >> 11, s = row & 2047;
            Kp[((size_t)(b * 16 + h) * 2048 + s) * 64 + (rr - 64)] =
                f2bf(acc[i][j][r] + bval);
          }
      } else {                // V transposed [d][s]: r=0..3 -> consecutive s
#pragma unroll
        for (int i = 0; i < 4; i++) {
          const int row0 = m0 + wm + i * 16 + fq * 4;   // +r stays in same b
          const int b = row0 >> 11, s = row0 & 2047;
          ushort4 o;
          o.x = f2bf(acc[i][j][0] + bval);
          o.y = f2bf(acc[i][j][1] + bval);
          o.z = f2bf(acc[i][j][2] + bval);
          o.w = f2bf(acc[i][j][3] + bval);
          *(ushort4*)(Vp + ((size_t)(b * 16 + h) * 64 + (rr - 128)) * 2048 + s) = o;
        }
      }
    }
  }
}

// ---------------- MFMA causal flash attention, S^T orientation ----------------
// Q [bh][s][64] (scaled by log2e/8), K [bh][s][64], VT [bh][d][s].
// S^T = K x Q^T. Block = 2 waves = 64 q; q-tiles PAIRED (qt, 31-qt) -> 1024
// uniform blocks, 4 resident blocks/CU (LDS 40960B). Double-buffered K/V
// staging, prefetch-before-compute, single end-of-tile barrier.
// Softmax denominator via ones-MFMA (R7). Offset-domain softmax + lazy
// max-reduce (R8, verified): running max folded into QK C-init; cross-lane
// reduce only inside the rare rescale branch. Byte-identical to passing R8.
__global__ __launch_bounds__(128, 2) void attn_k(
    const unsigned short* __restrict__ Qg, const unsigned short* __restrict__ Kg,
    const unsigned short* __restrict__ Vg, unsigned short* __restrict__ outa) {
  __shared__ __align__(16) unsigned short Ks[2 * 64 * 64];   // [buf][key][d] swz
  __shared__ __align__(16) unsigned short VTs[2 * 64 * 64];  // [buf][d][key] swz
  __shared__ __align__(16) unsigned short Ps[2 * 32 * 64];   // per-wave [q][key] swz
  const int tid = threadIdx.x;
  const int lane = tid & 63, wave = tid >> 6;
  const int fc = lane & 15, fq = lane >> 4, fc7 = fc & 7;
  // XCD swizzle: lin%8 = XCD -> give each XCD a contiguous 128-wg chunk (8 bh)
  const int wg = ((int)blockIdx.x & 7) * 128 + ((int)blockIdx.x >> 3);
  const int bh = wg >> 4, qx = wg & 15;
  const int b = bh >> 4, h = bh & 15;
  const int srow = lane >> 3;                   // 0..7 within 8-row chunk
  const int scol = ((lane & 7) ^ srow) * 8;     // swizzled global col (elems)
  const int pswz = fc & 14;                     // Ps 8B-block XOR swizzle
  const unsigned short* Qb = Qg + (size_t)bh * 2048 * 64;
  const unsigned short* Kb = Kg + (size_t)bh * 2048 * 64;
  const unsigned short* Vb = Vg + (size_t)bh * 64 * 2048;
  unsigned short* Pw = Ps + wave * 32 * 64;
  bf16x8 vones;                                 // bf16 1.0 x8 (A-operand)
#pragma unroll
  for (int j = 0; j < 8; j++) vones[j] = (short)0x3F80;

#pragma unroll 1
  for (int phase = 0; phase < 2; phase++) {
    const int qt = phase ? 31 - qx : qx;  // pair: 33 key-tiles total per block
    const int qw = qt * 64 + wave * 32;

    // Q B-frags: qb[g][s] = Q[qw+g*16+fc][s*32 + fq*8 + j]
    bf16x8 qb[2][2];
#pragma unroll
    for (int g = 0; g < 2; g++) {
      const unsigned short* qrow = Qb + (size_t)(qw + g * 16 + fc) * 64;
      qb[g][0] = *(const bf16x8*)(qrow + fq * 8);
      qb[g][1] = *(const bf16x8*)(qrow + 32 + fq * 8);
    }

    f32x4 O[4][2];
#pragma unroll
    for (int dt = 0; dt < 4; dt++)
#pragma unroll
      for (int g = 0; g < 2; g++) O[dt][g] = (f32x4){0.f, 0.f, 0.f, 0.f};
    f32x4 O1[2];                    // ones-row accumulator = softmax denom
#pragma unroll
    for (int g = 0; g < 2; g++) O1[g] = (f32x4){0.f, 0.f, 0.f, 0.f};
    f32x4 cz[2];                    // QK MFMA C-init = {-m}x4; m starts 0
#pragma unroll
    for (int g = 0; g < 2; g++) cz[g] = (f32x4){0.f, 0.f, 0.f, 0.f};

    // prologue: stage key-tile 0 into buffer 0
#pragma unroll
    for (int c = 0; c < 4; c++) {
      const int rbase = c * 16 + wave * 8;
      gl_lds16(Kb + (size_t)(rbase + srow) * 64 + scol, Ks + rbase * 64);
      gl_lds16(Vb + (size_t)(rbase + srow) * 2048 + scol, VTs + rbase * 64);
    }
    __syncthreads();  // implicit vmcnt(0): tile 0 resident

#pragma unroll 1
    for (int kb = 0; kb <= qt; kb++) {
      const int bsel = kb & 1;
      // prefetch tile kb+1 into the other buffer; latency hides under compute.
      if (kb < qt) {
        const size_t koff = (size_t)(kb + 1) * 4096;  // 64 rows * 64 elems
        const int voff = (kb + 1) * 64;
        unsigned short* Kd = Ks + (bsel ^ 1) * 4096;
        unsigned short* Vd = VTs + (bsel ^ 1) * 4096;
#pragma unroll
        for (int c = 0; c < 4; c++) {
          const int rbase = c * 16 + wave * 8;
          gl_lds16(Kb + koff + (size_t)(rbase + srow) * 64 + scol, Kd + rbase * 64);
          gl_lds16(Vb + (size_t)(rbase + srow) * 2048 + voff + scol, Vd + rbase * 64);
        }
      }
      const int k0 = kb * 64;
      const unsigned short* Ksb = Ks + bsel * 4096;
      const unsigned short* VTb = VTs + bsel * 4096;

      // S'^T = K x Q^T - m : row=key=k0+t*16+fq*4+r, col=q=qw+g*16+fc
      f32x4 S[4][2];
      __builtin_amdgcn_s_setprio(1);
#pragma unroll
      for (int t = 0; t < 4; t++) {
        bf16x8 ka0 = *(const bf16x8*)(Ksb + (t * 16 + fc) * 64 + ((fq ^ fc7) * 8));
        bf16x8 ka1 = *(const bf16x8*)(Ksb + (t * 16 + fc) * 64 + (((4 + fq) ^ fc7) * 8));
#pragma unroll
        for (int g = 0; g < 2; g++) {
          f32x4 s = __builtin_amdgcn_mfma_f32_16x16x32_bf16(ka0, qb[g][0], cz[g], 0, 0, 0);
          S[t][g] = __builtin_amdgcn_mfma_f32_16x16x32_bf16(ka1, qb[g][1], s, 0, 0, 0);
        }
      }
      __builtin_amdgcn_s_setprio(0);
      if (kb == qt) {  // diagonal tile: causal mask (wave-uniform branch)
#pragma unroll
        for (int t = 0; t < 4; t++)
#pragma unroll
          for (int g = 0; g < 2; g++)
#pragma unroll
            for (int r = 0; r < 4; r++)
              if (k0 + t * 16 + fq * 4 + r > qw + g * 16 + fc) S[t][g][r] = -3e38f;
      }
      // offset-domain online softmax; lazy reduce (common path: no shfl/sub)
      float alpha[2] = {1.f, 1.f};
      bool resc = false;
#pragma unroll
      for (int g = 0; g < 2; g++) {
        // max3-fusable tree over the 16 in-lane scores (local max only)
        float a0 = fmaxf(fmaxf(S[0][g][0], S[0][g][1]), S[0][g][2]);
        float a1 = fmaxf(fmaxf(S[0][g][3], S[1][g][0]), S[1][g][1]);
        float a2 = fmaxf(fmaxf(S[1][g][2], S[1][g][3]), S[2][g][0]);
        float a3 = fmaxf(fmaxf(S[2][g][1], S[2][g][2]), S[2][g][3]);
        float a4 = fmaxf(fmaxf(S[3][g][0], S[3][g][1]), S[3][g][2]);
        float b0 = fmaxf(fmaxf(a0, a1), a2);
        float b1 = fmaxf(fmaxf(a3, a4), S[3][g][3]);
        float cm = fmaxf(b0, b1);
        // trigger iff any q-row's tile-max exceeds m+8 (local check is
        // equivalent to reduced check under __all over the full wave)
        if (!__all(cm <= 8.0f)) {
          cm = fmaxf(cm, __shfl_xor(cm, 16, 64));   // per-q reduce (rare path)
          cm = fmaxf(cm, __shfl_xor(cm, 32, 64));
          const float delta = fmaxf(cm, 0.f);       // monotone m += delta
          alpha[g] = exp2_fast(-delta);
#pragma unroll
          for (int r = 0; r < 4; r++) cz[g][r] -= delta;
#pragma unroll
          for (int t = 0; t < 4; t++)
#pragma unroll
            for (int r = 0; r < 4; r++) S[t][g][r] -= delta;
          resc = true;
        }
#pragma unroll
        for (int t = 0; t < 4; t++)
#pragma unroll
          for (int r = 0; r < 4; r++) S[t][g][r] = exp2_fast(S[t][g][r]);
      }
      // P store [q][key]: 8B blocks, XOR(fc&14) swizzle (conflict-free @64 stride)
#pragma unroll
      for (int g = 0; g < 2; g++)
#pragma unroll
        for (int t = 0; t < 4; t++) {
          uint2 u;
          u.x = pk2bf(S[t][g][0], S[t][g][1]);
          u.y = pk2bf(S[t][g][2], S[t][g][3]);
          *(uint2*)(Pw + (g * 16 + fc) * 64 + (((t * 4 + fq) ^ pswz) * 4)) = u;
        }
      bf16x8 pb[2][2];
#pragma unroll
      for (int g = 0; g < 2; g++)
#pragma unroll
        for (int s = 0; s < 2; s++)
          pb[g][s] = *(const bf16x8*)(Pw + (g * 16 + fc) * 64 +
                                      (((s * 8 + fq * 2) ^ pswz) * 4));
      if (resc) {  // wave-uniform; rare
#pragma unroll
        for (int dt = 0; dt < 4; dt++)
#pragma unroll
          for (int g = 0; g < 2; g++)
#pragma unroll
            for (int r = 0; r < 4; r++) O[dt][g][r] *= alpha[g];
#pragma unroll
        for (int g = 0; g < 2; g++)
#pragma unroll
          for (int r = 0; r < 4; r++) O1[g][r] *= alpha[g];
      }
      // O^T += V^T x P ; denom row via ones-MFMA (full 64-key sum per lane)
      __builtin_amdgcn_s_setprio(1);
#pragma unroll
      for (int dt = 0; dt < 4; dt++) {
        bf16x8 va0 = *(const bf16x8*)(VTb + (dt * 16 + fc) * 64 + ((fq ^ fc7) * 8));
        bf16x8 va1 = *(const bf16x8*)(VTb + (dt * 16 + fc) * 64 + (((4 + fq) ^ fc7) * 8));
#pragma unroll
        for (int g = 0; g < 2; g++) {
          O[dt][g] = __builtin_amdgcn_mfma_f32_16x16x32_bf16(va0, pb[g][0], O[dt][g], 0, 0, 0);
          O[dt][g] = __builtin_amdgcn_mfma_f32_16x16x32_bf16(va1, pb[g][1], O[dt][g], 0, 0, 0);
        }
      }
#pragma unroll
      for (int g = 0; g < 2; g++) {
        O1[g] = __builtin_amdgcn_mfma_f32_16x16x32_bf16(vones, pb[g][0], O1[g], 0, 0, 0);
        O1[g] = __builtin_amdgcn_mfma_f32_16x16x32_bf16(vones, pb[g][1], O1[g], 0, 0, 0);
      }
      __builtin_amdgcn_s_setprio(0);
      // single barrier per tile; implicit vmcnt(0)+lgkmcnt(0) drain makes the
      // prefetched tile resident and all LDS reads complete -> next stage safe
      __syncthreads();
    }

    // epilogue: denom = O1 (full sum already in every lane; no reduce needed)
    float inv[2];
#pragma unroll
    for (int g = 0; g < 2; g++) inv[g] = 1.f / O1[g][0];
#pragma unroll
    for (int dt = 0; dt < 4; dt++)
#pragma unroll
      for (int g = 0; g < 2; g++) {
        uint2 u;
        u.x = pk2bf(O[dt][g][0] * inv[g], O[dt][g][1] * inv[g]);
        u.y = pk2bf(O[dt][g][2] * inv[g], O[dt][g][3] * inv[g]);
        size_t row = (size_t)(b * NS) + qw + g * 16 + fc;
        *(uint2*)(outa + row * 1024 + h * 64 + dt * 16 + fq * 4) = u;
      }
  }
}

// ---------------- launch ----------------
// ws (bf16 elems): xb[8192*1024] | wqkv[3072*1024] | wo[1024*1024]
//                  | Q[64*2048*64] | K[64*2048*64] | VT[64*64*2048] | att[8192*1024]
extern "C" void kernel_launch(void* const* d_in, const int* in_sizes, int n_in,
                              void* d_out, int out_size, void* d_ws, size_t ws_size,
                              hipStream_t stream) {
  const float* x     = (const float*)d_in[0];
  const float* qkv_w = (const float*)d_in[1];
  const float* qkv_b = (const float*)d_in[2];
  const float* out_w = (const float*)d_in[3];
  const float* out_b = (const float*)d_in[4];

  unsigned short* xb   = (unsigned short*)d_ws;
  unsigned short* wqkv = xb + (size_t)8192 * 1024;
  unsigned short* wo   = wqkv + (size_t)3072 * 1024;
  unsigned short* Qg   = wo + (size_t)1024 * 1024;
  unsigned short* Kg   = Qg + (size_t)64 * 2048 * 64;
  unsigned short* Vg   = Kg + (size_t)64 * 2048 * 64;
  unsigned short* att  = Vg + (size_t)64 * 64 * 2048;

  cast3_k<<<12288, 256, 0, stream>>>(x, qkv_w, out_w, xb);

  gemm_bt<1><<<dim3(24, 64), 256, 0, stream>>>(xb, wqkv, qkv_b, nullptr,
                                               Qg, Kg, Vg, 8192, 3072, 1024);
  attn_k<<<dim3(1024), 128, 0, stream>>>(Qg, Kg, Vg, att);
  gemm_bt<0><<<dim3(8, 64), 256, 0, stream>>>(att, wo, out_b, d_out,
                                              nullptr, nullptr, nullptr,
                                              8192, 1024, 1024);
}

// Round 10
// 245.099 us; speedup vs baseline: 1.0116x; 1.0116x over previous
//
#include <hip/hip_runtime.h>
#include <hip/hip_bf16.h>
#include <cstdint>

// Problem constants (fixed): B=4, S=2048, E=1024, H=16, HD=64
#define NB 4
#define NS 2048
#define NE 1024
#define NH 16

typedef __attribute__((ext_vector_type(8))) short bf16x8;   // 8 bf16 (4 VGPRs)
typedef __attribute__((ext_vector_type(4))) float f32x4;    // MFMA C/D

__device__ __forceinline__ unsigned short f2bf(float f) {
  unsigned u = __float_as_uint(f);
  u += 0x7fffu + ((u >> 16) & 1u);   // RNE
  return (unsigned short)(u >> 16);
}

// R10 single-variable experiment: v_cvt_pk_bf16_f32 (1 instr) replaces the
// 3-instr pk2bf (2x v_add + v_perm) in attn's P-pack. This is the isolated
// retest of one member of the R3/R4 NaN bundle. pass -> keep (-32 VALU/tile);
// NaN -> cvtpk confirmed culprit, permanent revert.
__device__ __forceinline__ unsigned cvtpk(float lo, float hi) {
  unsigned r;
  asm("v_cvt_pk_bf16_f32 %0, %1, %2" : "=v"(r) : "v"(lo), "v"(hi));
  return r;
}

__device__ __forceinline__ float exp2_fast(float x) {
#if __has_builtin(__builtin_amdgcn_exp2f)
  return __builtin_amdgcn_exp2f(x);
#else
  float r;
  asm("v_exp_f32 %0, %1" : "=v"(r) : "v"(x));
  return r;
#endif
}

// async global->LDS, 16B/lane. LDS dest = wave-uniform base + lane*16.
__device__ __forceinline__ void gl_lds16(const void* g, void* l) {
  __builtin_amdgcn_global_load_lds(
      (const __attribute__((address_space(1))) void*)g,
      (__attribute__((address_space(3))) void*)l, 16, 0, 0);
}

// ---------------- fused cast fp32 -> bf16 (x | qkv_w | out_w) ----------------
// Destinations are contiguous in ws in this exact order, so out[idx] works
// for all three ranges. Ranges in float4 units:
//   x:     [0, 2097152)          -> xb
//   qkv_w: [2097152, 2883584)    -> wqkv
//   out_w: [2883584, 3145728)    -> wo
// Grid = 3145728/256 = 12288 exact (no bounds check).
__global__ __launch_bounds__(256) void cast3_k(const float* __restrict__ x,
                                               const float* __restrict__ w1,
                                               const float* __restrict__ w2,
                                               unsigned short* __restrict__ out) {
  int idx = blockIdx.x * 256 + threadIdx.x;
  const float4* src;
  int local = idx;
  if (idx < 2097152) {
    src = (const float4*)x;
  } else if (idx < 2883584) {
    src = (const float4*)w1; local = idx - 2097152;
  } else {
    src = (const float4*)w2; local = idx - 2883584;
  }
  float4 v = src[local];
  ushort4 o;
  o.x = f2bf(v.x); o.y = f2bf(v.y); o.z = f2bf(v.z); o.w = f2bf(v.w);
  ((ushort4*)out)[idx] = o;
}

// ---------------- C = A[M,K] @ B[N,K]^T + bias ----------------
// 128x128 tile, 4 waves 2x2, 4x4 MFMA/wave, BK=64, global_load_lds staging.
// NO block swizzle (R5 post-mortem): with dim3(24,64), lin=24y+x and 24y%8==0
// so XCD = x%8 -> each XCD already owns 3 FIXED B-column-panels (768KB,
// L2-resident, reused across all 64 M-rows). Keep the natural mapping.
// Epilogue (R9, verified): Q/K/V category wave-uniform per j -> hoisted
// branch; V packed as ushort4 (4x fewer stores, 8B/lane granularity).
template <int MODE>
__global__ __launch_bounds__(256, 2) void gemm_bt(
    const unsigned short* __restrict__ A,   // [M,K] bf16
    const unsigned short* __restrict__ Bm,  // [N,K] bf16
    const float* __restrict__ bias,         // [N] fp32
    void* __restrict__ Cv,                  // MODE0: fp32 [M,N]
    unsigned short* __restrict__ Qp,        // MODE1: [bh][s][64]
    unsigned short* __restrict__ Kp,        // MODE1: [bh][s][64]
    unsigned short* __restrict__ Vp,        // MODE1: [bh][d][s]
    int M, int N, int K) {
  __shared__ __align__(16) unsigned short As[128 * 64];
  __shared__ __align__(16) unsigned short Bs[128 * 64];
  const int tid = threadIdx.x;
  const int lane = tid & 63, wave = tid >> 6;
  const int m0 = blockIdx.y * 128, n0 = blockIdx.x * 128;
  const int wm = (wave >> 1) * 64, wn = (wave & 1) * 64;
  const int fr = lane & 15, fq = lane >> 4;

  f32x4 acc[4][4];
#pragma unroll
  for (int i = 0; i < 4; i++)
#pragma unroll
    for (int j = 0; j < 4; j++) acc[i][j] = (f32x4){0.f, 0.f, 0.f, 0.f};

  const int srow = lane >> 3;                   // 0..7 within 8-row chunk
  const int scol = ((lane & 7) ^ srow) * 8;     // swizzled global col (elems)

  for (int kt = 0; kt < K; kt += 64) {
    __syncthreads();
#pragma unroll
    for (int c = 0; c < 4; c++) {
      const int chunk = wave * 4 + c;           // 0..15, 8 rows each
      const int row = chunk * 8 + srow;
      gl_lds16(A + (size_t)(m0 + row) * K + kt + scol, As + chunk * 512);
      gl_lds16(Bm + (size_t)(n0 + row) * K + kt + scol, Bs + chunk * 512);
    }
    __syncthreads();
#pragma unroll
    for (int s = 0; s < 2; s++) {
      bf16x8 af[4], bf[4];
#pragma unroll
      for (int i = 0; i < 4; i++)
        af[i] = *(const bf16x8*)(As + (wm + i * 16 + fr) * 64 +
                                 (((s * 4 + fq) ^ (fr & 7)) * 8));
#pragma unroll
      for (int j = 0; j < 4; j++)
        bf[j] = *(const bf16x8*)(Bs + (wn + j * 16 + fr) * 64 +
                                 (((s * 4 + fq) ^ (fr & 7)) * 8));
#pragma unroll
      for (int i = 0; i < 4; i++)
#pragma unroll
        for (int j = 0; j < 4; j++)
          acc[i][j] = __builtin_amdgcn_mfma_f32_16x16x32_bf16(af[i], bf[j], acc[i][j], 0, 0, 0);
    }
  }

#pragma unroll
  for (int j = 0; j < 4; j++) {
    const int col = n0 + wn + j * 16 + fr;
    const float bval = bias[col];
    if (MODE == 0) {
#pragma unroll
      for (int i = 0; i < 4; i++)
#pragma unroll
        for (int r = 0; r < 4; r++) {
          const int row = m0 + wm + i * 16 + fq * 4 + r;
          ((float*)Cv)[(size_t)row * N + col] = acc[i][j][r] + bval;
        }
    } else {
      const int h = col / 192, rr = col - h * 192;
      if (rr < 64) {          // Q, pre-scaled into exp2 domain
#pragma unroll
        for (int i = 0; i < 4; i++)
#pragma unroll
          for (int r = 0; r < 4; r++) {
            const int row = m0 + wm + i * 16 + fq * 4 + r;
            const int b = row >> 11, s = row & 2047;
            Qp[((size_t)(b * 16 + h) * 2048 + s) * 64 + rr] =
                f2bf((acc[i][j][r] + bval) * 0.1803368802f);
          }
      } else if (rr < 128) {  // K
#pragma unroll
        for (int i = 0; i < 4; i++)
#pragma unroll
          for (int r = 0; r < 4; r++) {
            const int row = m0 + wm + i * 16 + fq * 4 + r;
            const int b = row >> 11, s = row & 2047;
            Kp[((size_t)(b * 16 + h) * 2048 + s) * 64 + (rr - 64)] =
                f2bf(acc[i][j][r] + bval);
          }
      } else {                // V transposed [d][s]: r=0..3 -> consecutive s
#pragma unroll
        for (int i = 0; i < 4; i++) {
          const int row0 = m0 + wm + i * 16 + fq * 4;   // +r stays in same b
          const int b = row0 >> 11, s = row0 & 2047;
          ushort4 o;
          o.x = f2bf(acc[i][j][0] + bval);
          o.y = f2bf(acc[i][j][1] + bval);
          o.z = f2bf(acc[i][j][2] + bval);
          o.w = f2bf(acc[i][j][3] + bval);
          *(ushort4*)(Vp + ((size_t)(b * 16 + h) * 64 + (rr - 128)) * 2048 + s) = o;
        }
      }
    }
  }
}

// ---------------- MFMA causal flash attention, S^T orientation ----------------
// Q [bh][s][64] (scaled by log2e/8), K [bh][s][64], VT [bh][d][s].
// S^T = K x Q^T. Block = 2 waves = 64 q; q-tiles PAIRED (qt, 31-qt) -> 1024
// uniform blocks, 4 resident blocks/CU (LDS 40960B). Double-buffered K/V
// staging, prefetch-before-compute, single end-of-tile barrier.
// Softmax denominator via ones-MFMA (R7). Offset-domain softmax + lazy
// max-reduce (R8): running max folded into QK C-init; cross-lane reduce only
// inside the rare rescale branch.
// R10: pk2bf -> v_cvt_pk_bf16_f32 in P-pack + epilogue (ONLY change vs R9).
__global__ __launch_bounds__(128, 2) void attn_k(
    const unsigned short* __restrict__ Qg, const unsigned short* __restrict__ Kg,
    const unsigned short* __restrict__ Vg, unsigned short* __restrict__ outa) {
  __shared__ __align__(16) unsigned short Ks[2 * 64 * 64];   // [buf][key][d] swz
  __shared__ __align__(16) unsigned short VTs[2 * 64 * 64];  // [buf][d][key] swz
  __shared__ __align__(16) unsigned short Ps[2 * 32 * 64];   // per-wave [q][key] swz
  const int tid = threadIdx.x;
  const int lane = tid & 63, wave = tid >> 6;
  const int fc = lane & 15, fq = lane >> 4, fc7 = fc & 7;
  // XCD swizzle: lin%8 = XCD -> give each XCD a contiguous 128-wg chunk (8 bh)
  const int wg = ((int)blockIdx.x & 7) * 128 + ((int)blockIdx.x >> 3);
  const int bh = wg >> 4, qx = wg & 15;
  const int b = bh >> 4, h = bh & 15;
  const int srow = lane >> 3;                   // 0..7 within 8-row chunk
  const int scol = ((lane & 7) ^ srow) * 8;     // swizzled global col (elems)
  const int pswz = fc & 14;                     // Ps 8B-block XOR swizzle
  const unsigned short* Qb = Qg + (size_t)bh * 2048 * 64;
  const unsigned short* Kb = Kg + (size_t)bh * 2048 * 64;
  const unsigned short* Vb = Vg + (size_t)bh * 64 * 2048;
  unsigned short* Pw = Ps + wave * 32 * 64;
  bf16x8 vones;                                 // bf16 1.0 x8 (A-operand)
#pragma unroll
  for (int j = 0; j < 8; j++) vones[j] = (short)0x3F80;

#pragma unroll 1
  for (int phase = 0; phase < 2; phase++) {
    const int qt = phase ? 31 - qx : qx;  // pair: 33 key-tiles total per block
    const int qw = qt * 64 + wave * 32;

    // Q B-frags: qb[g][s] = Q[qw+g*16+fc][s*32 + fq*8 + j]
    bf16x8 qb[2][2];
#pragma unroll
    for (int g = 0; g < 2; g++) {
      const unsigned short* qrow = Qb + (size_t)(qw + g * 16 + fc) * 64;
      qb[g][0] = *(const bf16x8*)(qrow + fq * 8);
      qb[g][1] = *(const bf16x8*)(qrow + 32 + fq * 8);
    }

    f32x4 O[4][2];
#pragma unroll
    for (int dt = 0; dt < 4; dt++)
#pragma unroll
      for (int g = 0; g < 2; g++) O[dt][g] = (f32x4){0.f, 0.f, 0.f, 0.f};
    f32x4 O1[2];                    // ones-row accumulator = softmax denom
#pragma unroll
    for (int g = 0; g < 2; g++) O1[g] = (f32x4){0.f, 0.f, 0.f, 0.f};
    f32x4 cz[2];                    // QK MFMA C-init = {-m}x4; m starts 0
#pragma unroll
    for (int g = 0; g < 2; g++) cz[g] = (f32x4){0.f, 0.f, 0.f, 0.f};

    // prologue: stage key-tile 0 into buffer 0
#pragma unroll
    for (int c = 0; c < 4; c++) {
      const int rbase = c * 16 + wave * 8;
      gl_lds16(Kb + (size_t)(rbase + srow) * 64 + scol, Ks + rbase * 64);
      gl_lds16(Vb + (size_t)(rbase + srow) * 2048 + scol, VTs + rbase * 64);
    }
    __syncthreads();  // implicit vmcnt(0): tile 0 resident

#pragma unroll 1
    for (int kb = 0; kb <= qt; kb++) {
      const int bsel = kb & 1;
      // prefetch tile kb+1 into the other buffer; latency hides under compute.
      if (kb < qt) {
        const size_t koff = (size_t)(kb + 1) * 4096;  // 64 rows * 64 elems
        const int voff = (kb + 1) * 64;
        unsigned short* Kd = Ks + (bsel ^ 1) * 4096;
        unsigned short* Vd = VTs + (bsel ^ 1) * 4096;
#pragma unroll
        for (int c = 0; c < 4; c++) {
          const int rbase = c * 16 + wave * 8;
          gl_lds16(Kb + koff + (size_t)(rbase + srow) * 64 + scol, Kd + rbase * 64);
          gl_lds16(Vb + (size_t)(rbase + srow) * 2048 + voff + scol, Vd + rbase * 64);
        }
      }
      const int k0 = kb * 64;
      const unsigned short* Ksb = Ks + bsel * 4096;
      const unsigned short* VTb = VTs + bsel * 4096;

      // S'^T = K x Q^T - m : row=key=k0+t*16+fq*4+r, col=q=qw+g*16+fc
      f32x4 S[4][2];
      __builtin_amdgcn_s_setprio(1);
#pragma unroll
      for (int t = 0; t < 4; t++) {
        bf16x8 ka0 = *(const bf16x8*)(Ksb + (t * 16 + fc) * 64 + ((fq ^ fc7) * 8));
        bf16x8 ka1 = *(const bf16x8*)(Ksb + (t * 16 + fc) * 64 + (((4 + fq) ^ fc7) * 8));
#pragma unroll
        for (int g = 0; g < 2; g++) {
          f32x4 s = __builtin_amdgcn_mfma_f32_16x16x32_bf16(ka0, qb[g][0], cz[g], 0, 0, 0);
          S[t][g] = __builtin_amdgcn_mfma_f32_16x16x32_bf16(ka1, qb[g][1], s, 0, 0, 0);
        }
      }
      __builtin_amdgcn_s_setprio(0);
      if (kb == qt) {  // diagonal tile: causal mask (wave-uniform branch)
#pragma unroll
        for (int t = 0; t < 4; t++)
#pragma unroll
          for (int g = 0; g < 2; g++)
#pragma unroll
            for (int r = 0; r < 4; r++)
              if (k0 + t * 16 + fq * 4 + r > qw + g * 16 + fc) S[t][g][r] = -3e38f;
      }
      // offset-domain online softmax; lazy reduce (common path: no shfl/sub)
      float alpha[2] = {1.f, 1.f};
      bool resc = false;
#pragma unroll
      for (int g = 0; g < 2; g++) {
        // max3-fusable tree over the 16 in-lane scores (local max only)
        float a0 = fmaxf(fmaxf(S[0][g][0], S[0][g][1]), S[0][g][2]);
        float a1 = fmaxf(fmaxf(S[0][g][3], S[1][g][0]), S[1][g][1]);
        float a2 = fmaxf(fmaxf(S[1][g][2], S[1][g][3]), S[2][g][0]);
        float a3 = fmaxf(fmaxf(S[2][g][1], S[2][g][2]), S[2][g][3]);
        float a4 = fmaxf(fmaxf(S[3][g][0], S[3][g][1]), S[3][g][2]);
        float b0 = fmaxf(fmaxf(a0, a1), a2);
        float b1 = fmaxf(fmaxf(a3, a4), S[3][g][3]);
        float cm = fmaxf(b0, b1);
        // trigger iff any q-row's tile-max exceeds m+8 (local check is
        // equivalent to reduced check under __all over the full wave)
        if (!__all(cm <= 8.0f)) {
          cm = fmaxf(cm, __shfl_xor(cm, 16, 64));   // per-q reduce (rare path)
          cm = fmaxf(cm, __shfl_xor(cm, 32, 64));
          const float delta = fmaxf(cm, 0.f);       // monotone m += delta
          alpha[g] = exp2_fast(-delta);
#pragma unroll
          for (int r = 0; r < 4; r++) cz[g][r] -= delta;
#pragma unroll
          for (int t = 0; t < 4; t++)
#pragma unroll
            for (int r = 0; r < 4; r++) S[t][g][r] -= delta;
          resc = true;
        }
#pragma unroll
        for (int t = 0; t < 4; t++)
#pragma unroll
          for (int r = 0; r < 4; r++) S[t][g][r] = exp2_fast(S[t][g][r]);
      }
      // P store [q][key]: 8B blocks, XOR(fc&14) swizzle (conflict-free @64 stride)
#pragma unroll
      for (int g = 0; g < 2; g++)
#pragma unroll
        for (int t = 0; t < 4; t++) {
          uint2 u;
          u.x = cvtpk(S[t][g][0], S[t][g][1]);
          u.y = cvtpk(S[t][g][2], S[t][g][3]);
          *(uint2*)(Pw + (g * 16 + fc) * 64 + (((t * 4 + fq) ^ pswz) * 4)) = u;
        }
      bf16x8 pb[2][2];
#pragma unroll
      for (int g = 0; g < 2; g++)
#pragma unroll
        for (int s = 0; s < 2; s++)
          pb[g][s] = *(const bf16x8*)(Pw + (g * 16 + fc) * 64 +
                                      (((s * 8 + fq * 2) ^ pswz) * 4));
      if (resc) {  // wave-uniform; rare
#pragma unroll
        for (int dt = 0; dt < 4; dt++)
#pragma unroll
          for (int g = 0; g < 2; g++)
#pragma unroll
            for (int r = 0; r < 4; r++) O[dt][g][r] *= alpha[g];
#pragma unroll
        for (int g = 0; g < 2; g++)
#pragma unroll
          for (int r = 0; r < 4; r++) O1[g][r] *= alpha[g];
      }
      // O^T += V^T x P ; denom row via ones-MFMA (full 64-key sum per lane)
      __builtin_amdgcn_s_setprio(1);
#pragma unroll
      for (int dt = 0; dt < 4; dt++) {
        bf16x8 va0 = *(const bf16x8*)(VTb + (dt * 16 + fc) * 64 + ((fq ^ fc7) * 8));
        bf16x8 va1 = *(const bf16x8*)(VTb + (dt * 16 + fc) * 64 + (((4 + fq) ^ fc7) * 8));
#pragma unroll
        for (int g = 0; g < 2; g++) {
          O[dt][g] = __builtin_amdgcn_mfma_f32_16x16x32_bf16(va0, pb[g][0], O[dt][g], 0, 0, 0);
          O[dt][g] = __builtin_amdgcn_mfma_f32_16x16x32_bf16(va1, pb[g][1], O[dt][g], 0, 0, 0);
        }
      }
#pragma unroll
      for (int g = 0; g < 2; g++) {
        O1[g] = __builtin_amdgcn_mfma_f32_16x16x32_bf16(vones, pb[g][0], O1[g], 0, 0, 0);
        O1[g] = __builtin_amdgcn_mfma_f32_16x16x32_bf16(vones, pb[g][1], O1[g], 0, 0, 0);
      }
      __builtin_amdgcn_s_setprio(0);
      // single barrier per tile; implicit vmcnt(0)+lgkmcnt(0) drain makes the
      // prefetched tile resident and all LDS reads complete -> next stage safe
      __syncthreads();
    }

    // epilogue: denom = O1 (full sum already in every lane; no reduce needed)
    float inv[2];
#pragma unroll
    for (int g = 0; g < 2; g++) inv[g] = 1.f / O1[g][0];
#pragma unroll
    for (int dt = 0; dt < 4; dt++)
#pragma unroll
      for (int g = 0; g < 2; g++) {
        uint2 u;
        u.x = cvtpk(O[dt][g][0] * inv[g], O[dt][g][1] * inv[g]);
        u.y = cvtpk(O[dt][g][2] * inv[g], O[dt][g][3] * inv[g]);
        size_t row = (size_t)(b * NS) + qw + g * 16 + fc;
        *(uint2*)(outa + row * 1024 + h * 64 + dt * 16 + fq * 4) = u;
      }
  }
}

// ---------------- launch ----------------
// ws (bf16 elems): xb[8192*1024] | wqkv[3072*1024] | wo[1024*1024]
//                  | Q[64*2048*64] | K[64*2048*64] | VT[64*64*2048] | att[8192*1024]
extern "C" void kernel_launch(void* const* d_in, const int* in_sizes, int n_in,
                              void* d_out, int out_size, void* d_ws, size_t ws_size,
                              hipStream_t stream) {
  const float* x     = (const float*)d_in[0];
  const float* qkv_w = (const float*)d_in[1];
  const float* qkv_b = (const float*)d_in[2];
  const float* out_w = (const float*)d_in[3];
  const float* out_b = (const float*)d_in[4];

  unsigned short* xb   = (unsigned short*)d_ws;
  unsigned short* wqkv = xb + (size_t)8192 * 1024;
  unsigned short* wo   = wqkv + (size_t)3072 * 1024;
  unsigned short* Qg   = wo + (size_t)1024 * 1024;
  unsigned short* Kg   = Qg + (size_t)64 * 2048 * 64;
  unsigned short* Vg   = Kg + (size_t)64 * 2048 * 64;
  unsigned short* att  = Vg + (size_t)64 * 64 * 2048;

  cast3_k<<<12288, 256, 0, stream>>>(x, qkv_w, out_w, xb);

  gemm_bt<1><<<dim3(24, 64), 256, 0, stream>>>(xb, wqkv, qkv_b, nullptr,
                                               Qg, Kg, Vg, 8192, 3072, 1024);
  attn_k<<<dim3(1024), 128, 0, stream>>>(Qg, Kg, Vg, att);
  gemm_bt<0><<<dim3(8, 64), 256, 0, stream>>>(att, wo, out_b, d_out,
                                              nullptr, nullptr, nullptr,
                                              8192, 1024, 1024);
}

// Round 11
// 243.736 us; speedup vs baseline: 1.0173x; 1.0056x over previous
//
#include <hip/hip_runtime.h>
#include <hip/hip_bf16.h>
#include <cstdint>

// Problem constants (fixed): B=4, S=2048, E=1024, H=16, HD=64
#define NB 4
#define NS 2048
#define NE 1024
#define NH 16

typedef __attribute__((ext_vector_type(8))) short bf16x8;   // 8 bf16 (4 VGPRs)
typedef __attribute__((ext_vector_type(4))) float f32x4;    // MFMA C/D

__device__ __forceinline__ unsigned short f2bf(float f) {
  unsigned u = __float_as_uint(f);
  u += 0x7fffu + ((u >> 16) & 1u);   // RNE
  return (unsigned short)(u >> 16);
}

// v_cvt_pk_bf16_f32: pack two fp32 -> bf16x2 in one instr (R10, verified)
__device__ __forceinline__ unsigned cvtpk(float lo, float hi) {
  unsigned r;
  asm("v_cvt_pk_bf16_f32 %0, %1, %2" : "=v"(r) : "v"(lo), "v"(hi));
  return r;
}

__device__ __forceinline__ float exp2_fast(float x) {
#if __has_builtin(__builtin_amdgcn_exp2f)
  return __builtin_amdgcn_exp2f(x);
#else
  float r;
  asm("v_exp_f32 %0, %1" : "=v"(r) : "v"(x));
  return r;
#endif
}

// async global->LDS, 16B/lane. LDS dest = wave-uniform base + lane*16.
__device__ __forceinline__ void gl_lds16(const void* g, void* l) {
  __builtin_amdgcn_global_load_lds(
      (const __attribute__((address_space(1))) void*)g,
      (__attribute__((address_space(3))) void*)l, 16, 0, 0);
}

// ---------------- fused cast fp32 -> bf16 (x | qkv_w | out_w) ----------------
// Destinations are contiguous in ws in this exact order, so out[idx] works
// for all three ranges. Ranges in float4 units:
//   x:     [0, 2097152)          -> xb
//   qkv_w: [2097152, 2883584)    -> wqkv
//   out_w: [2883584, 3145728)    -> wo
// Grid = 3145728/256 = 12288 exact (no bounds check).
__global__ __launch_bounds__(256) void cast3_k(const float* __restrict__ x,
                                               const float* __restrict__ w1,
                                               const float* __restrict__ w2,
                                               unsigned short* __restrict__ out) {
  int idx = blockIdx.x * 256 + threadIdx.x;
  const float4* src;
  int local = idx;
  if (idx < 2097152) {
    src = (const float4*)x;
  } else if (idx < 2883584) {
    src = (const float4*)w1; local = idx - 2097152;
  } else {
    src = (const float4*)w2; local = idx - 2883584;
  }
  float4 v = src[local];
  ushort4 o;
  o.x = f2bf(v.x); o.y = f2bf(v.y); o.z = f2bf(v.z); o.w = f2bf(v.w);
  ((ushort4*)out)[idx] = o;
}

// ---------------- C = A[M,K] @ B[N,K]^T + bias ----------------
// 128x128 tile, 4 waves 2x2, 4x4 MFMA/wave, BK=64, global_load_lds staging.
// NO block swizzle (R5 post-mortem): with dim3(24,64), lin=24y+x and 24y%8==0
// so XCD = x%8 -> each XCD already owns 3 FIXED B-column-panels (768KB,
// L2-resident, reused across all 64 M-rows). Keep the natural mapping.
// Epilogue (R9): Q/K/V category wave-uniform per j -> hoisted branch;
// V packed as ushort4 (4x fewer stores, 8B/lane granularity).
// R11: K-loop software pipeline, same pattern proven in attn_k (R1):
// double-buffered As/Bs (LDS 64KB, residency stays 2 blocks/CU = 128KB),
// prefetch k+1 issued BEFORE compute of k, single end-of-iteration barrier
// whose implicit vmcnt(0)+lgkmcnt(0) is the counted wait -> the ~500-900cy
// global->LDS latency hides under the ~600cy MFMA+ds_read compute phase
// instead of being serially exposed at a mid-loop barrier.
// Race-free: buf[bsel^1] was last READ before the previous barrier; its
// restaging writes can't land until the next barrier (vmcnt drain), after
// compute of buf[bsel] has finished.
template <int MODE>
__global__ __launch_bounds__(256, 2) void gemm_bt(
    const unsigned short* __restrict__ A,   // [M,K] bf16
    const unsigned short* __restrict__ Bm,  // [N,K] bf16
    const float* __restrict__ bias,         // [N] fp32
    void* __restrict__ Cv,                  // MODE0: fp32 [M,N]
    unsigned short* __restrict__ Qp,        // MODE1: [bh][s][64]
    unsigned short* __restrict__ Kp,        // MODE1: [bh][s][64]
    unsigned short* __restrict__ Vp,        // MODE1: [bh][d][s]
    int M, int N, int K) {
  __shared__ __align__(16) unsigned short As[2 * 128 * 64];
  __shared__ __align__(16) unsigned short Bs[2 * 128 * 64];
  const int tid = threadIdx.x;
  const int lane = tid & 63, wave = tid >> 6;
  const int m0 = blockIdx.y * 128, n0 = blockIdx.x * 128;
  const int wm = (wave >> 1) * 64, wn = (wave & 1) * 64;
  const int fr = lane & 15, fq = lane >> 4;

  f32x4 acc[4][4];
#pragma unroll
  for (int i = 0; i < 4; i++)
#pragma unroll
    for (int j = 0; j < 4; j++) acc[i][j] = (f32x4){0.f, 0.f, 0.f, 0.f};

  const int srow = lane >> 3;                   // 0..7 within 8-row chunk
  const int scol = ((lane & 7) ^ srow) * 8;     // swizzled global col (elems)
  // hoisted per-thread staging bases (row part of the address)
  const unsigned short* Ast = A + (size_t)(m0 + wave * 32 + srow) * K + scol;
  const unsigned short* Bst = Bm + (size_t)(n0 + wave * 32 + srow) * K + scol;

  const int nk = K >> 6;
  // prologue: stage K-step 0 into buffer 0
#pragma unroll
  for (int c = 0; c < 4; c++) {
    gl_lds16(Ast + (size_t)c * 8 * K, As + (wave * 4 + c) * 512);
    gl_lds16(Bst + (size_t)c * 8 * K, Bs + (wave * 4 + c) * 512);
  }
  __syncthreads();  // implicit vmcnt(0): step 0 resident

  for (int ki = 0; ki < nk; ki++) {
    const int bsel = ki & 1;
    if (ki + 1 < nk) {  // prefetch next K-step into the other buffer
      const int kt = (ki + 1) << 6;
      unsigned short* Ad = As + (bsel ^ 1) * 8192;
      unsigned short* Bd = Bs + (bsel ^ 1) * 8192;
#pragma unroll
      for (int c = 0; c < 4; c++) {
        gl_lds16(Ast + (size_t)c * 8 * K + kt, Ad + (wave * 4 + c) * 512);
        gl_lds16(Bst + (size_t)c * 8 * K + kt, Bd + (wave * 4 + c) * 512);
      }
    }
    const unsigned short* Asb = As + bsel * 8192;
    const unsigned short* Bsb = Bs + bsel * 8192;
#pragma unroll
    for (int s = 0; s < 2; s++) {
      bf16x8 af[4], bf[4];
#pragma unroll
      for (int i = 0; i < 4; i++)
        af[i] = *(const bf16x8*)(Asb + (wm + i * 16 + fr) * 64 +
                                 (((s * 4 + fq) ^ (fr & 7)) * 8));
#pragma unroll
      for (int j = 0; j < 4; j++)
        bf[j] = *(const bf16x8*)(Bsb + (wn + j * 16 + fr) * 64 +
                                 (((s * 4 + fq) ^ (fr & 7)) * 8));
#pragma unroll
      for (int i = 0; i < 4; i++)
#pragma unroll
        for (int j = 0; j < 4; j++)
          acc[i][j] = __builtin_amdgcn_mfma_f32_16x16x32_bf16(af[i], bf[j], acc[i][j], 0, 0, 0);
    }
    __syncthreads();  // drains prefetch (vmcnt) + ds_reads (lgkm)
  }

#pragma unroll
  for (int j = 0; j < 4; j++) {
    const int col = n0 + wn + j * 16 + fr;
    const float bval = bias[col];
    if (MODE == 0) {
#pragma unroll
      for (int i = 0; i < 4; i++)
#pragma unroll
        for (int r = 0; r < 4; r++) {
          const int row = m0 + wm + i * 16 + fq * 4 + r;
          ((float*)Cv)[(size_t)row * N + col] = acc[i][j][r] + bval;
        }
    } else {
      const int h = col / 192, rr = col - h * 192;
      if (rr < 64) {          // Q, pre-scaled into exp2 domain
#pragma unroll
        for (int i = 0; i < 4; i++)
#pragma unroll
          for (int r = 0; r < 4; r++) {
            const int row = m0 + wm + i * 16 + fq * 4 + r;
            const int b = row >> 11, s = row & 2047;
            Qp[((size_t)(b * 16 + h) * 2048 + s) * 64 + rr] =
                f2bf((acc[i][j][r] + bval) * 0.1803368802f);
          }
      } else if (rr < 128) {  // K
#pragma unroll
        for (int i = 0; i < 4; i++)
#pragma unroll
          for (int r = 0; r < 4; r++) {
            const int row = m0 + wm + i * 16 + fq * 4 + r;
            const int b = row >> 11, s = row & 2047;
            Kp[((size_t)(b * 16 + h) * 2048 + s) * 64 + (rr - 64)] =
                f2bf(acc[i][j][r] + bval);
          }
      } else {                // V transposed [d][s]: r=0..3 -> consecutive s
#pragma unroll
        for (int i = 0; i < 4; i++) {
          const int row0 = m0 + wm + i * 16 + fq * 4;   // +r stays in same b
          const int b = row0 >> 11, s = row0 & 2047;
          ushort4 o;
          o.x = f2bf(acc[i][j][0] + bval);
          o.y = f2bf(acc[i][j][1] + bval);
          o.z = f2bf(acc[i][j][2] + bval);
          o.w = f2bf(acc[i][j][3] + bval);
          *(ushort4*)(Vp + ((size_t)(b * 16 + h) * 64 + (rr - 128)) * 2048 + s) = o;
        }
      }
    }
  }
}

// ---------------- MFMA causal flash attention, S^T orientation ----------------
// Q [bh][s][64] (scaled by log2e/8), K [bh][s][64], VT [bh][d][s].
// S^T = K x Q^T. Block = 2 waves = 64 q; q-tiles PAIRED (qt, 31-qt) -> 1024
// uniform blocks, 4 resident blocks/CU (LDS 40960B). Double-buffered K/V
// staging, prefetch-before-compute, single end-of-tile barrier.
// Softmax denominator via ones-MFMA (R7). Offset-domain softmax + lazy
// max-reduce (R8). cvt_pk_bf16 pack (R10). Byte-identical to passing R10.
__global__ __launch_bounds__(128, 2) void attn_k(
    const unsigned short* __restrict__ Qg, const unsigned short* __restrict__ Kg,
    const unsigned short* __restrict__ Vg, unsigned short* __restrict__ outa) {
  __shared__ __align__(16) unsigned short Ks[2 * 64 * 64];   // [buf][key][d] swz
  __shared__ __align__(16) unsigned short VTs[2 * 64 * 64];  // [buf][d][key] swz
  __shared__ __align__(16) unsigned short Ps[2 * 32 * 64];   // per-wave [q][key] swz
  const int tid = threadIdx.x;
  const int lane = tid & 63, wave = tid >> 6;
  const int fc = lane & 15, fq = lane >> 4, fc7 = fc & 7;
  // XCD swizzle: lin%8 = XCD -> give each XCD a contiguous 128-wg chunk (8 bh)
  const int wg = ((int)blockIdx.x & 7) * 128 + ((int)blockIdx.x >> 3);
  const int bh = wg >> 4, qx = wg & 15;
  const int b = bh >> 4, h = bh & 15;
  const int srow = lane >> 3;                   // 0..7 within 8-row chunk
  const int scol = ((lane & 7) ^ srow) * 8;     // swizzled global col (elems)
  const int pswz = fc & 14;                     // Ps 8B-block XOR swizzle
  const unsigned short* Qb = Qg + (size_t)bh * 2048 * 64;
  const unsigned short* Kb = Kg + (size_t)bh * 2048 * 64;
  const unsigned short* Vb = Vg + (size_t)bh * 64 * 2048;
  unsigned short* Pw = Ps + wave * 32 * 64;
  bf16x8 vones;                                 // bf16 1.0 x8 (A-operand)
#pragma unroll
  for (int j = 0; j < 8; j++) vones[j] = (short)0x3F80;

#pragma unroll 1
  for (int phase = 0; phase < 2; phase++) {
    const int qt = phase ? 31 - qx : qx;  // pair: 33 key-tiles total per block
    const int qw = qt * 64 + wave * 32;

    // Q B-frags: qb[g][s] = Q[qw+g*16+fc][s*32 + fq*8 + j]
    bf16x8 qb[2][2];
#pragma unroll
    for (int g = 0; g < 2; g++) {
      const unsigned short* qrow = Qb + (size_t)(qw + g * 16 + fc) * 64;
      qb[g][0] = *(const bf16x8*)(qrow + fq * 8);
      qb[g][1] = *(const bf16x8*)(qrow + 32 + fq * 8);
    }

    f32x4 O[4][2];
#pragma unroll
    for (int dt = 0; dt < 4; dt++)
#pragma unroll
      for (int g = 0; g < 2; g++) O[dt][g] = (f32x4){0.f, 0.f, 0.f, 0.f};
    f32x4 O1[2];                    // ones-row accumulator = softmax denom
#pragma unroll
    for (int g = 0; g < 2; g++) O1[g] = (f32x4){0.f, 0.f, 0.f, 0.f};
    f32x4 cz[2];                    // QK MFMA C-init = {-m}x4; m starts 0
#pragma unroll
    for (int g = 0; g < 2; g++) cz[g] = (f32x4){0.f, 0.f, 0.f, 0.f};

    // prologue: stage key-tile 0 into buffer 0
#pragma unroll
    for (int c = 0; c < 4; c++) {
      const int rbase = c * 16 + wave * 8;
      gl_lds16(Kb + (size_t)(rbase + srow) * 64 + scol, Ks + rbase * 64);
      gl_lds16(Vb + (size_t)(rbase + srow) * 2048 + scol, VTs + rbase * 64);
    }
    __syncthreads();  // implicit vmcnt(0): tile 0 resident

#pragma unroll 1
    for (int kb = 0; kb <= qt; kb++) {
      const int bsel = kb & 1;
      // prefetch tile kb+1 into the other buffer; latency hides under compute.
      if (kb < qt) {
        const size_t koff = (size_t)(kb + 1) * 4096;  // 64 rows * 64 elems
        const int voff = (kb + 1) * 64;
        unsigned short* Kd = Ks + (bsel ^ 1) * 4096;
        unsigned short* Vd = VTs + (bsel ^ 1) * 4096;
#pragma unroll
        for (int c = 0; c < 4; c++) {
          const int rbase = c * 16 + wave * 8;
          gl_lds16(Kb + koff + (size_t)(rbase + srow) * 64 + scol, Kd + rbase * 64);
          gl_lds16(Vb + (size_t)(rbase + srow) * 2048 + voff + scol, Vd + rbase * 64);
        }
      }
      const int k0 = kb * 64;
      const unsigned short* Ksb = Ks + bsel * 4096;
      const unsigned short* VTb = VTs + bsel * 4096;

      // S'^T = K x Q^T - m : row=key=k0+t*16+fq*4+r, col=q=qw+g*16+fc
      f32x4 S[4][2];
      __builtin_amdgcn_s_setprio(1);
#pragma unroll
      for (int t = 0; t < 4; t++) {
        bf16x8 ka0 = *(const bf16x8*)(Ksb + (t * 16 + fc) * 64 + ((fq ^ fc7) * 8));
        bf16x8 ka1 = *(const bf16x8*)(Ksb + (t * 16 + fc) * 64 + (((4 + fq) ^ fc7) * 8));
#pragma unroll
        for (int g = 0; g < 2; g++) {
          f32x4 s = __builtin_amdgcn_mfma_f32_16x16x32_bf16(ka0, qb[g][0], cz[g], 0, 0, 0);
          S[t][g] = __builtin_amdgcn_mfma_f32_16x16x32_bf16(ka1, qb[g][1], s, 0, 0, 0);
        }
      }
      __builtin_amdgcn_s_setprio(0);
      if (kb == qt) {  // diagonal tile: causal mask (wave-uniform branch)
#pragma unroll
        for (int t = 0; t < 4; t++)
#pragma unroll
          for (int g = 0; g < 2; g++)
#pragma unroll
            for (int r = 0; r < 4; r++)
              if (k0 + t * 16 + fq * 4 + r > qw + g * 16 + fc) S[t][g][r] = -3e38f;
      }
      // offset-domain online softmax; lazy reduce (common path: no shfl/sub)
      float alpha[2] = {1.f, 1.f};
      bool resc = false;
#pragma unroll
      for (int g = 0; g < 2; g++) {
        // max3-fusable tree over the 16 in-lane scores (local max only)
        float a0 = fmaxf(fmaxf(S[0][g][0], S[0][g][1]), S[0][g][2]);
        float a1 = fmaxf(fmaxf(S[0][g][3], S[1][g][0]), S[1][g][1]);
        float a2 = fmaxf(fmaxf(S[1][g][2], S[1][g][3]), S[2][g][0]);
        float a3 = fmaxf(fmaxf(S[2][g][1], S[2][g][2]), S[2][g][3]);
        float a4 = fmaxf(fmaxf(S[3][g][0], S[3][g][1]), S[3][g][2]);
        float b0 = fmaxf(fmaxf(a0, a1), a2);
        float b1 = fmaxf(fmaxf(a3, a4), S[3][g][3]);
        float cm = fmaxf(b0, b1);
        // trigger iff any q-row's tile-max exceeds m+8 (local check is
        // equivalent to reduced check under __all over the full wave)
        if (!__all(cm <= 8.0f)) {
          cm = fmaxf(cm, __shfl_xor(cm, 16, 64));   // per-q reduce (rare path)
          cm = fmaxf(cm, __shfl_xor(cm, 32, 64));
          const float delta = fmaxf(cm, 0.f);       // monotone m += delta
          alpha[g] = exp2_fast(-delta);
#pragma unroll
          for (int r = 0; r < 4; r++) cz[g][r] -= delta;
#pragma unroll
          for (int t = 0; t < 4; t++)
#pragma unroll
            for (int r = 0; r < 4; r++) S[t][g][r] -= delta;
          resc = true;
        }
#pragma unroll
        for (int t = 0; t < 4; t++)
#pragma unroll
          for (int r = 0; r < 4; r++) S[t][g][r] = exp2_fast(S[t][g][r]);
      }
      // P store [q][key]: 8B blocks, XOR(fc&14) swizzle (conflict-free @64 stride)
#pragma unroll
      for (int g = 0; g < 2; g++)
#pragma unroll
        for (int t = 0; t < 4; t++) {
          uint2 u;
          u.x = cvtpk(S[t][g][0], S[t][g][1]);
          u.y = cvtpk(S[t][g][2], S[t][g][3]);
          *(uint2*)(Pw + (g * 16 + fc) * 64 + (((t * 4 + fq) ^ pswz) * 4)) = u;
        }
      bf16x8 pb[2][2];
#pragma unroll
      for (int g = 0; g < 2; g++)
#pragma unroll
        for (int s = 0; s < 2; s++)
          pb[g][s] = *(const bf16x8*)(Pw + (g * 16 + fc) * 64 +
                                      (((s * 8 + fq * 2) ^ pswz) * 4));
      if (resc) {  // wave-uniform; rare
#pragma unroll
        for (int dt = 0; dt < 4; dt++)
#pragma unroll
          for (int g = 0; g < 2; g++)
#pragma unroll
            for (int r = 0; r < 4; r++) O[dt][g][r] *= alpha[g];
#pragma unroll
        for (int g = 0; g < 2; g++)
#pragma unroll
          for (int r = 0; r < 4; r++) O1[g][r] *= alpha[g];
      }
      // O^T += V^T x P ; denom row via ones-MFMA (full 64-key sum per lane)
      __builtin_amdgcn_s_setprio(1);
#pragma unroll
      for (int dt = 0; dt < 4; dt++) {
        bf16x8 va0 = *(const bf16x8*)(VTb + (dt * 16 + fc) * 64 + ((fq ^ fc7) * 8));
        bf16x8 va1 = *(const bf16x8*)(VTb + (dt * 16 + fc) * 64 + (((4 + fq) ^ fc7) * 8));
#pragma unroll
        for (int g = 0; g < 2; g++) {
          O[dt][g] = __builtin_amdgcn_mfma_f32_16x16x32_bf16(va0, pb[g][0], O[dt][g], 0, 0, 0);
          O[dt][g] = __builtin_amdgcn_mfma_f32_16x16x32_bf16(va1, pb[g][1], O[dt][g], 0, 0, 0);
        }
      }
#pragma unroll
      for (int g = 0; g < 2; g++) {
        O1[g] = __builtin_amdgcn_mfma_f32_16x16x32_bf16(vones, pb[g][0], O1[g], 0, 0, 0);
        O1[g] = __builtin_amdgcn_mfma_f32_16x16x32_bf16(vones, pb[g][1], O1[g], 0, 0, 0);
      }
      __builtin_amdgcn_s_setprio(0);
      // single barrier per tile; implicit vmcnt(0)+lgkmcnt(0) drain makes the
      // prefetched tile resident and all LDS reads complete -> next stage safe
      __syncthreads();
    }

    // epilogue: denom = O1 (full sum already in every lane; no reduce needed)
    float inv[2];
#pragma unroll
    for (int g = 0; g < 2; g++) inv[g] = 1.f / O1[g][0];
#pragma unroll
    for (int dt = 0; dt < 4; dt++)
#pragma unroll
      for (int g = 0; g < 2; g++) {
        uint2 u;
        u.x = cvtpk(O[dt][g][0] * inv[g], O[dt][g][1] * inv[g]);
        u.y = cvtpk(O[dt][g][2] * inv[g], O[dt][g][3] * inv[g]);
        size_t row = (size_t)(b * NS) + qw + g * 16 + fc;
        *(uint2*)(outa + row * 1024 + h * 64 + dt * 16 + fq * 4) = u;
      }
  }
}

// ---------------- launch ----------------
// ws (bf16 elems): xb[8192*1024] | wqkv[3072*1024] | wo[1024*1024]
//                  | Q[64*2048*64] | K[64*2048*64] | VT[64*64*2048] | att[8192*1024]
extern "C" void kernel_launch(void* const* d_in, const int* in_sizes, int n_in,
                              void* d_out, int out_size, void* d_ws, size_t ws_size,
                              hipStream_t stream) {
  const float* x     = (const float*)d_in[0];
  const float* qkv_w = (const float*)d_in[1];
  const float* qkv_b = (const float*)d_in[2];
  const float* out_w = (const float*)d_in[3];
  const float* out_b = (const float*)d_in[4];

  unsigned short* xb   = (unsigned short*)d_ws;
  unsigned short* wqkv = xb + (size_t)8192 * 1024;
  unsigned short* wo   = wqkv + (size_t)3072 * 1024;
  unsigned short* Qg   = wo + (size_t)1024 * 1024;
  unsigned short* Kg   = Qg + (size_t)64 * 2048 * 64;
  unsigned short* Vg   = Kg + (size_t)64 * 2048 * 64;
  unsigned short* att  = Vg + (size_t)64 * 64 * 2048;

  cast3_k<<<12288, 256, 0, stream>>>(x, qkv_w, out_w, xb);

  gemm_bt<1><<<dim3(24, 64), 256, 0, stream>>>(xb, wqkv, qkv_b, nullptr,
                                               Qg, Kg, Vg, 8192, 3072, 1024);
  attn_k<<<dim3(1024), 128, 0, stream>>>(Qg, Kg, Vg, att);
  gemm_bt<0><<<dim3(8, 64), 256, 0, stream>>>(att, wo, out_b, d_out,
                                              nullptr, nullptr, nullptr,
                                              8192, 1024, 1024);
}

// Round 12
// 237.372 us; speedup vs baseline: 1.0446x; 1.0268x over previous
//
#include <hip/hip_runtime.h>
#include <hip/hip_bf16.h>
#include <cstdint>

// Problem constants (fixed): B=4, S=2048, E=1024, H=16, HD=64
#define NB 4
#define NS 2048
#define NE 1024
#define NH 16

typedef __attribute__((ext_vector_type(8))) short bf16x8;   // 8 bf16 (4 VGPRs)
typedef __attribute__((ext_vector_type(4))) float f32x4;    // MFMA C/D

__device__ __forceinline__ unsigned short f2bf(float f) {
  unsigned u = __float_as_uint(f);
  u += 0x7fffu + ((u >> 16) & 1u);   // RNE
  return (unsigned short)(u >> 16);
}

// v_cvt_pk_bf16_f32: pack two fp32 -> bf16x2 in one instr (R10, verified)
__device__ __forceinline__ unsigned cvtpk(float lo, float hi) {
  unsigned r;
  asm("v_cvt_pk_bf16_f32 %0, %1, %2" : "=v"(r) : "v"(lo), "v"(hi));
  return r;
}

__device__ __forceinline__ float exp2_fast(float x) {
#if __has_builtin(__builtin_amdgcn_exp2f)
  return __builtin_amdgcn_exp2f(x);
#else
  float r;
  asm("v_exp_f32 %0, %1" : "=v"(r) : "v"(x));
  return r;
#endif
}

// async global->LDS, 16B/lane. LDS dest = wave-uniform base + lane*16.
__device__ __forceinline__ void gl_lds16(const void* g, void* l) {
  __builtin_amdgcn_global_load_lds(
      (const __attribute__((address_space(1))) void*)g,
      (__attribute__((address_space(3))) void*)l, 16, 0, 0);
}

// ---------------- fused cast fp32 -> bf16 (x | qkv_w | out_w) ----------------
// Destinations are contiguous in ws in this exact order, so out[idx] works
// for all three ranges. Ranges in float4 units:
//   x:     [0, 2097152)          -> xb
//   qkv_w: [2097152, 2883584)    -> wqkv
//   out_w: [2883584, 3145728)    -> wo
// Grid = 3145728/256 = 12288 exact (no bounds check).
__global__ __launch_bounds__(256) void cast3_k(const float* __restrict__ x,
                                               const float* __restrict__ w1,
                                               const float* __restrict__ w2,
                                               unsigned short* __restrict__ out) {
  int idx = blockIdx.x * 256 + threadIdx.x;
  const float4* src;
  int local = idx;
  if (idx < 2097152) {
    src = (const float4*)x;
  } else if (idx < 2883584) {
    src = (const float4*)w1; local = idx - 2097152;
  } else {
    src = (const float4*)w2; local = idx - 2883584;
  }
  float4 v = src[local];
  ushort4 o;
  o.x = f2bf(v.x); o.y = f2bf(v.y); o.z = f2bf(v.z); o.w = f2bf(v.w);
  ((ushort4*)out)[idx] = o;
}

// ---------------- C = A[M,K] @ B[N,K]^T + bias ----------------
// 128x128 tile, 4 waves 2x2, 4x4 MFMA/wave, BK=64, global_load_lds staging.
// R12: REVERTED to R10's single-buffer 2-barrier K-loop. R11's double-buffer
// (LDS 64KB, VGPR 88) dropped occupancy 27->19% and cost +5us (71.0 vs <=66.4
// measured) - TLP loss beat latency hiding, the m132 lesson. At ~780 TF this
// 128^2 structure is ~85% of its own ceiling; only the 8-phase 256^2 rewrite
// goes further.
// NO block swizzle (R5): with dim3(24,64), XCD = x%8 -> each XCD owns 3 fixed
// B-column-panels (768KB, L2-resident). Epilogue (R9): category wave-uniform
// per j -> hoisted branch; V packed as ushort4.
template <int MODE>
__global__ __launch_bounds__(256, 2) void gemm_bt(
    const unsigned short* __restrict__ A,   // [M,K] bf16
    const unsigned short* __restrict__ Bm,  // [N,K] bf16
    const float* __restrict__ bias,         // [N] fp32
    void* __restrict__ Cv,                  // MODE0: fp32 [M,N]
    unsigned short* __restrict__ Qp,        // MODE1: [bh][s][64]
    unsigned short* __restrict__ Kp,        // MODE1: [bh][s][64]
    unsigned short* __restrict__ Vp,        // MODE1: [bh][d][s]
    int M, int N, int K) {
  __shared__ __align__(16) unsigned short As[128 * 64];
  __shared__ __align__(16) unsigned short Bs[128 * 64];
  const int tid = threadIdx.x;
  const int lane = tid & 63, wave = tid >> 6;
  const int m0 = blockIdx.y * 128, n0 = blockIdx.x * 128;
  const int wm = (wave >> 1) * 64, wn = (wave & 1) * 64;
  const int fr = lane & 15, fq = lane >> 4;

  f32x4 acc[4][4];
#pragma unroll
  for (int i = 0; i < 4; i++)
#pragma unroll
    for (int j = 0; j < 4; j++) acc[i][j] = (f32x4){0.f, 0.f, 0.f, 0.f};

  const int srow = lane >> 3;                   // 0..7 within 8-row chunk
  const int scol = ((lane & 7) ^ srow) * 8;     // swizzled global col (elems)

  for (int kt = 0; kt < K; kt += 64) {
    __syncthreads();
#pragma unroll
    for (int c = 0; c < 4; c++) {
      const int chunk = wave * 4 + c;           // 0..15, 8 rows each
      const int row = chunk * 8 + srow;
      gl_lds16(A + (size_t)(m0 + row) * K + kt + scol, As + chunk * 512);
      gl_lds16(Bm + (size_t)(n0 + row) * K + kt + scol, Bs + chunk * 512);
    }
    __syncthreads();
#pragma unroll
    for (int s = 0; s < 2; s++) {
      bf16x8 af[4], bf[4];
#pragma unroll
      for (int i = 0; i < 4; i++)
        af[i] = *(const bf16x8*)(As + (wm + i * 16 + fr) * 64 +
                                 (((s * 4 + fq) ^ (fr & 7)) * 8));
#pragma unroll
      for (int j = 0; j < 4; j++)
        bf[j] = *(const bf16x8*)(Bs + (wn + j * 16 + fr) * 64 +
                                 (((s * 4 + fq) ^ (fr & 7)) * 8));
#pragma unroll
      for (int i = 0; i < 4; i++)
#pragma unroll
        for (int j = 0; j < 4; j++)
          acc[i][j] = __builtin_amdgcn_mfma_f32_16x16x32_bf16(af[i], bf[j], acc[i][j], 0, 0, 0);
    }
  }

#pragma unroll
  for (int j = 0; j < 4; j++) {
    const int col = n0 + wn + j * 16 + fr;
    const float bval = bias[col];
    if (MODE == 0) {
#pragma unroll
      for (int i = 0; i < 4; i++)
#pragma unroll
        for (int r = 0; r < 4; r++) {
          const int row = m0 + wm + i * 16 + fq * 4 + r;
          ((float*)Cv)[(size_t)row * N + col] = acc[i][j][r] + bval;
        }
    } else {
      const int h = col / 192, rr = col - h * 192;
      if (rr < 64) {          // Q, pre-scaled into exp2 domain
#pragma unroll
        for (int i = 0; i < 4; i++)
#pragma unroll
          for (int r = 0; r < 4; r++) {
            const int row = m0 + wm + i * 16 + fq * 4 + r;
            const int b = row >> 11, s = row & 2047;
            Qp[((size_t)(b * 16 + h) * 2048 + s) * 64 + rr] =
                f2bf((acc[i][j][r] + bval) * 0.1803368802f);
          }
      } else if (rr < 128) {  // K
#pragma unroll
        for (int i = 0; i < 4; i++)
#pragma unroll
          for (int r = 0; r < 4; r++) {
            const int row = m0 + wm + i * 16 + fq * 4 + r;
            const int b = row >> 11, s = row & 2047;
            Kp[((size_t)(b * 16 + h) * 2048 + s) * 64 + (rr - 64)] =
                f2bf(acc[i][j][r] + bval);
          }
      } else {                // V transposed [d][s]: r=0..3 -> consecutive s
#pragma unroll
        for (int i = 0; i < 4; i++) {
          const int row0 = m0 + wm + i * 16 + fq * 4;   // +r stays in same b
          const int b = row0 >> 11, s = row0 & 2047;
          ushort4 o;
          o.x = f2bf(acc[i][j][0] + bval);
          o.y = f2bf(acc[i][j][1] + bval);
          o.z = f2bf(acc[i][j][2] + bval);
          o.w = f2bf(acc[i][j][3] + bval);
          *(ushort4*)(Vp + ((size_t)(b * 16 + h) * 64 + (rr - 128)) * 2048 + s) = o;
        }
      }
    }
  }
}

// ---------------- MFMA causal flash attention, S^T orientation ----------------
// Q [bh][s][64] (scaled by log2e/8), K [bh][s][64], VT [bh][d][s].
// S^T = K x Q^T. Block = 2 waves = 64 q; q-tiles PAIRED (qt, 31-qt) -> 1024
// uniform blocks, 4 resident blocks/CU (LDS 40960B). Double-buffered K/V
// staging, prefetch-before-compute, single end-of-tile barrier.
// Ones-MFMA denominator (R7). Offset-domain softmax + lazy max-reduce (R8).
// cvt_pk_bf16 pack (R10).
// R12 single-variable experiment: P pack+store+pb-load folded INTO the per-g
// softmax loop (PV stays unified after both g). g0's ~150cy P store->load LDS
// round-trip hides under g1's ~200cy softmax VALU. Same-wave DS ordering
// (stores issue before loads, DS executes in order) is the same guarantee the
// working store-then-load pattern relies on. This isolates the "per-g
// interleave" suspect of the R3/R4 NaN WITHOUT the VT-hoist/PV-split.
__global__ __launch_bounds__(128, 2) void attn_k(
    const unsigned short* __restrict__ Qg, const unsigned short* __restrict__ Kg,
    const unsigned short* __restrict__ Vg, unsigned short* __restrict__ outa) {
  __shared__ __align__(16) unsigned short Ks[2 * 64 * 64];   // [buf][key][d] swz
  __shared__ __align__(16) unsigned short VTs[2 * 64 * 64];  // [buf][d][key] swz
  __shared__ __align__(16) unsigned short Ps[2 * 32 * 64];   // per-wave [q][key] swz
  const int tid = threadIdx.x;
  const int lane = tid & 63, wave = tid >> 6;
  const int fc = lane & 15, fq = lane >> 4, fc7 = fc & 7;
  // XCD swizzle: lin%8 = XCD -> give each XCD a contiguous 128-wg chunk (8 bh)
  const int wg = ((int)blockIdx.x & 7) * 128 + ((int)blockIdx.x >> 3);
  const int bh = wg >> 4, qx = wg & 15;
  const int b = bh >> 4, h = bh & 15;
  const int srow = lane >> 3;                   // 0..7 within 8-row chunk
  const int scol = ((lane & 7) ^ srow) * 8;     // swizzled global col (elems)
  const int pswz = fc & 14;                     // Ps 8B-block XOR swizzle
  const unsigned short* Qb = Qg + (size_t)bh * 2048 * 64;
  const unsigned short* Kb = Kg + (size_t)bh * 2048 * 64;
  const unsigned short* Vb = Vg + (size_t)bh * 64 * 2048;
  unsigned short* Pw = Ps + wave * 32 * 64;
  bf16x8 vones;                                 // bf16 1.0 x8 (A-operand)
#pragma unroll
  for (int j = 0; j < 8; j++) vones[j] = (short)0x3F80;

#pragma unroll 1
  for (int phase = 0; phase < 2; phase++) {
    const int qt = phase ? 31 - qx : qx;  // pair: 33 key-tiles total per block
    const int qw = qt * 64 + wave * 32;

    // Q B-frags: qb[g][s] = Q[qw+g*16+fc][s*32 + fq*8 + j]
    bf16x8 qb[2][2];
#pragma unroll
    for (int g = 0; g < 2; g++) {
      const unsigned short* qrow = Qb + (size_t)(qw + g * 16 + fc) * 64;
      qb[g][0] = *(const bf16x8*)(qrow + fq * 8);
      qb[g][1] = *(const bf16x8*)(qrow + 32 + fq * 8);
    }

    f32x4 O[4][2];
#pragma unroll
    for (int dt = 0; dt < 4; dt++)
#pragma unroll
      for (int g = 0; g < 2; g++) O[dt][g] = (f32x4){0.f, 0.f, 0.f, 0.f};
    f32x4 O1[2];                    // ones-row accumulator = softmax denom
#pragma unroll
    for (int g = 0; g < 2; g++) O1[g] = (f32x4){0.f, 0.f, 0.f, 0.f};
    f32x4 cz[2];                    // QK MFMA C-init = {-m}x4; m starts 0
#pragma unroll
    for (int g = 0; g < 2; g++) cz[g] = (f32x4){0.f, 0.f, 0.f, 0.f};

    // prologue: stage key-tile 0 into buffer 0
#pragma unroll
    for (int c = 0; c < 4; c++) {
      const int rbase = c * 16 + wave * 8;
      gl_lds16(Kb + (size_t)(rbase + srow) * 64 + scol, Ks + rbase * 64);
      gl_lds16(Vb + (size_t)(rbase + srow) * 2048 + scol, VTs + rbase * 64);
    }
    __syncthreads();  // implicit vmcnt(0): tile 0 resident

#pragma unroll 1
    for (int kb = 0; kb <= qt; kb++) {
      const int bsel = kb & 1;
      // prefetch tile kb+1 into the other buffer; latency hides under compute.
      if (kb < qt) {
        const size_t koff = (size_t)(kb + 1) * 4096;  // 64 rows * 64 elems
        const int voff = (kb + 1) * 64;
        unsigned short* Kd = Ks + (bsel ^ 1) * 4096;
        unsigned short* Vd = VTs + (bsel ^ 1) * 4096;
#pragma unroll
        for (int c = 0; c < 4; c++) {
          const int rbase = c * 16 + wave * 8;
          gl_lds16(Kb + koff + (size_t)(rbase + srow) * 64 + scol, Kd + rbase * 64);
          gl_lds16(Vb + (size_t)(rbase + srow) * 2048 + voff + scol, Vd + rbase * 64);
        }
      }
      const int k0 = kb * 64;
      const unsigned short* Ksb = Ks + bsel * 4096;
      const unsigned short* VTb = VTs + bsel * 4096;

      // S'^T = K x Q^T - m : row=key=k0+t*16+fq*4+r, col=q=qw+g*16+fc
      f32x4 S[4][2];
      __builtin_amdgcn_s_setprio(1);
#pragma unroll
      for (int t = 0; t < 4; t++) {
        bf16x8 ka0 = *(const bf16x8*)(Ksb + (t * 16 + fc) * 64 + ((fq ^ fc7) * 8));
        bf16x8 ka1 = *(const bf16x8*)(Ksb + (t * 16 + fc) * 64 + (((4 + fq) ^ fc7) * 8));
#pragma unroll
        for (int g = 0; g < 2; g++) {
          f32x4 s = __builtin_amdgcn_mfma_f32_16x16x32_bf16(ka0, qb[g][0], cz[g], 0, 0, 0);
          S[t][g] = __builtin_amdgcn_mfma_f32_16x16x32_bf16(ka1, qb[g][1], s, 0, 0, 0);
        }
      }
      __builtin_amdgcn_s_setprio(0);
      if (kb == qt) {  // diagonal tile: causal mask (wave-uniform branch)
#pragma unroll
        for (int t = 0; t < 4; t++)
#pragma unroll
          for (int g = 0; g < 2; g++)
#pragma unroll
            for (int r = 0; r < 4; r++)
              if (k0 + t * 16 + fq * 4 + r > qw + g * 16 + fc) S[t][g][r] = -3e38f;
      }
      // offset-domain online softmax; lazy reduce (common path: no shfl/sub).
      // R12: pack+store+load folded per-g so g0's P LDS round-trip overlaps
      // g1's softmax VALU.
      float alpha[2] = {1.f, 1.f};
      bool resc = false;
      bf16x8 pb[2][2];
#pragma unroll
      for (int g = 0; g < 2; g++) {
        // max3-fusable tree over the 16 in-lane scores (local max only)
        float a0 = fmaxf(fmaxf(S[0][g][0], S[0][g][1]), S[0][g][2]);
        float a1 = fmaxf(fmaxf(S[0][g][3], S[1][g][0]), S[1][g][1]);
        float a2 = fmaxf(fmaxf(S[1][g][2], S[1][g][3]), S[2][g][0]);
        float a3 = fmaxf(fmaxf(S[2][g][1], S[2][g][2]), S[2][g][3]);
        float a4 = fmaxf(fmaxf(S[3][g][0], S[3][g][1]), S[3][g][2]);
        float b0 = fmaxf(fmaxf(a0, a1), a2);
        float b1 = fmaxf(fmaxf(a3, a4), S[3][g][3]);
        float cm = fmaxf(b0, b1);
        // trigger iff any q-row's tile-max exceeds m+8 (local check is
        // equivalent to reduced check under __all over the full wave)
        if (!__all(cm <= 8.0f)) {
          cm = fmaxf(cm, __shfl_xor(cm, 16, 64));   // per-q reduce (rare path)
          cm = fmaxf(cm, __shfl_xor(cm, 32, 64));
          const float delta = fmaxf(cm, 0.f);       // monotone m += delta
          alpha[g] = exp2_fast(-delta);
#pragma unroll
          for (int r = 0; r < 4; r++) cz[g][r] -= delta;
#pragma unroll
          for (int t = 0; t < 4; t++)
#pragma unroll
            for (int r = 0; r < 4; r++) S[t][g][r] -= delta;
          resc = true;
        }
#pragma unroll
        for (int t = 0; t < 4; t++)
#pragma unroll
          for (int r = 0; r < 4; r++) S[t][g][r] = exp2_fast(S[t][g][r]);
        // P pack+store for this g: 8B blocks, XOR(fc&14) swizzle
#pragma unroll
        for (int t = 0; t < 4; t++) {
          uint2 u;
          u.x = cvtpk(S[t][g][0], S[t][g][1]);
          u.y = cvtpk(S[t][g][2], S[t][g][3]);
          *(uint2*)(Pw + (g * 16 + fc) * 64 + (((t * 4 + fq) ^ pswz) * 4)) = u;
        }
        // pb load for this g (round-trip hides under next g's softmax)
        pb[g][0] = *(const bf16x8*)(Pw + (g * 16 + fc) * 64 + (((fq * 2) ^ pswz) * 4));
        pb[g][1] = *(const bf16x8*)(Pw + (g * 16 + fc) * 64 + (((8 + fq * 2) ^ pswz) * 4));
      }
      if (resc) {  // wave-uniform; rare
#pragma unroll
        for (int dt = 0; dt < 4; dt++)
#pragma unroll
          for (int g = 0; g < 2; g++)
#pragma unroll
            for (int r = 0; r < 4; r++) O[dt][g][r] *= alpha[g];
#pragma unroll
        for (int g = 0; g < 2; g++)
#pragma unroll
          for (int r = 0; r < 4; r++) O1[g][r] *= alpha[g];
      }
      // O^T += V^T x P ; denom row via ones-MFMA (full 64-key sum per lane)
      __builtin_amdgcn_s_setprio(1);
#pragma unroll
      for (int dt = 0; dt < 4; dt++) {
        bf16x8 va0 = *(const bf16x8*)(VTb + (dt * 16 + fc) * 64 + ((fq ^ fc7) * 8));
        bf16x8 va1 = *(const bf16x8*)(VTb + (dt * 16 + fc) * 64 + (((4 + fq) ^ fc7) * 8));
#pragma unroll
        for (int g = 0; g < 2; g++) {
          O[dt][g] = __builtin_amdgcn_mfma_f32_16x16x32_bf16(va0, pb[g][0], O[dt][g], 0, 0, 0);
          O[dt][g] = __builtin_amdgcn_mfma_f32_16x16x32_bf16(va1, pb[g][1], O[dt][g], 0, 0, 0);
        }
      }
#pragma unroll
      for (int g = 0; g < 2; g++) {
        O1[g] = __builtin_amdgcn_mfma_f32_16x16x32_bf16(vones, pb[g][0], O1[g], 0, 0, 0);
        O1[g] = __builtin_amdgcn_mfma_f32_16x16x32_bf16(vones, pb[g][1], O1[g], 0, 0, 0);
      }
      __builtin_amdgcn_s_setprio(0);
      // single barrier per tile; implicit vmcnt(0)+lgkmcnt(0) drain makes the
      // prefetched tile resident and all LDS reads complete -> next stage safe
      __syncthreads();
    }

    // epilogue: denom = O1 (full sum already in every lane; no reduce needed)
    float inv[2];
#pragma unroll
    for (int g = 0; g < 2; g++) inv[g] = 1.f / O1[g][0];
#pragma unroll
    for (int dt = 0; dt < 4; dt++)
#pragma unroll
      for (int g = 0; g < 2; g++) {
        uint2 u;
        u.x = cvtpk(O[dt][g][0] * inv[g], O[dt][g][1] * inv[g]);
        u.y = cvtpk(O[dt][g][2] * inv[g], O[dt][g][3] * inv[g]);
        size_t row = (size_t)(b * NS) + qw + g * 16 + fc;
        *(uint2*)(outa + row * 1024 + h * 64 + dt * 16 + fq * 4) = u;
      }
  }
}

// ---------------- launch ----------------
// ws (bf16 elems): xb[8192*1024] | wqkv[3072*1024] | wo[1024*1024]
//                  | Q[64*2048*64] | K[64*2048*64] | VT[64*64*2048] | att[8192*1024]
extern "C" void kernel_launch(void* const* d_in, const int* in_sizes, int n_in,
                              void* d_out, int out_size, void* d_ws, size_t ws_size,
                              hipStream_t stream) {
  const float* x     = (const float*)d_in[0];
  const float* qkv_w = (const float*)d_in[1];
  const float* qkv_b = (const float*)d_in[2];
  const float* out_w = (const float*)d_in[3];
  const float* out_b = (const float*)d_in[4];

  unsigned short* xb   = (unsigned short*)d_ws;
  unsigned short* wqkv = xb + (size_t)8192 * 1024;
  unsigned short* wo   = wqkv + (size_t)3072 * 1024;
  unsigned short* Qg   = wo + (size_t)1024 * 1024;
  unsigned short* Kg   = Qg + (size_t)64 * 2048 * 64;
  unsigned short* Vg   = Kg + (size_t)64 * 2048 * 64;
  unsigned short* att  = Vg + (size_t)64 * 64 * 2048;

  cast3_k<<<12288, 256, 0, stream>>>(x, qkv_w, out_w, xb);

  gemm_bt<1><<<dim3(24, 64), 256, 0, stream>>>(xb, wqkv, qkv_b, nullptr,
                                               Qg, Kg, Vg, 8192, 3072, 1024);
  attn_k<<<dim3(1024), 128, 0, stream>>>(Qg, Kg, Vg, att);
  gemm_bt<0><<<dim3(8, 64), 256, 0, stream>>>(att, wo, out_b, d_out,
                                              nullptr, nullptr, nullptr,
                                              8192, 1024, 1024);
}

// Round 15
// 229.100 us; speedup vs baseline: 1.0823x; 1.0361x over previous
//
#include <hip/hip_runtime.h>
#include <hip/hip_bf16.h>
#include <cstdint>

// Problem constants (fixed): B=4, S=2048, E=1024, H=16, HD=64
#define NB 4
#define NS 2048
#define NE 1024
#define NH 16

typedef __attribute__((ext_vector_type(8))) short bf16x8;   // 8 bf16 (4 VGPRs)
typedef __attribute__((ext_vector_type(4))) float f32x4;    // MFMA C/D

__device__ __forceinline__ unsigned short f2bf(float f) {
  unsigned u = __float_as_uint(f);
  u += 0x7fffu + ((u >> 16) & 1u);   // RNE
  return (unsigned short)(u >> 16);
}

// v_cvt_pk_bf16_f32: pack two fp32 -> bf16x2 in one instr (R10, verified)
__device__ __forceinline__ unsigned cvtpk(float lo, float hi) {
  unsigned r;
  asm("v_cvt_pk_bf16_f32 %0, %1, %2" : "=v"(r) : "v"(lo), "v"(hi));
  return r;
}

__device__ __forceinline__ float exp2_fast(float x) {
#if __has_builtin(__builtin_amdgcn_exp2f)
  return __builtin_amdgcn_exp2f(x);
#else
  float r;
  asm("v_exp_f32 %0, %1" : "=v"(r) : "v"(x));
  return r;
#endif
}

// async global->LDS, 16B/lane. LDS dest = wave-uniform base + lane*16.
__device__ __forceinline__ void gl_lds16(const void* g, void* l) {
  __builtin_amdgcn_global_load_lds(
      (const __attribute__((address_space(1))) void*)g,
      (__attribute__((address_space(3))) void*)l, 16, 0, 0);
}

// ---------------- fused cast fp32 -> bf16 (x | qkv_w | out_w) ----------------
// Destinations are contiguous in ws in this exact order, so out[idx] works
// for all three ranges. Ranges in float4 units:
//   x:     [0, 2097152)          -> xb
//   qkv_w: [2097152, 2883584)    -> wqkv
//   out_w: [2883584, 3145728)    -> wo
// Grid = 3145728/256 = 12288 exact (no bounds check).
__global__ __launch_bounds__(256) void cast3_k(const float* __restrict__ x,
                                               const float* __restrict__ w1,
                                               const float* __restrict__ w2,
                                               unsigned short* __restrict__ out) {
  int idx = blockIdx.x * 256 + threadIdx.x;
  const float4* src;
  int local = idx;
  if (idx < 2097152) {
    src = (const float4*)x;
  } else if (idx < 2883584) {
    src = (const float4*)w1; local = idx - 2097152;
  } else {
    src = (const float4*)w2; local = idx - 2883584;
  }
  float4 v = src[local];
  ushort4 o;
  o.x = f2bf(v.x); o.y = f2bf(v.y); o.z = f2bf(v.z); o.w = f2bf(v.w);
  ((ushort4*)out)[idx] = o;
}

// ---------------- C = A[M,K] @ B[N,K]^T + bias ----------------
// 128x128 tile, 4 waves 2x2, 4x4 MFMA/wave, BK=64, global_load_lds staging.
// Single-buffer 2-barrier K-loop (R12-verified; R11 dbuf cost occupancy).
// R15: __launch_bounds__ min-waves 2 -> 3. Occupancy measured 27% (~2
// blocks/CU) while LDS (32KB -> 5 blocks) and unified VGPR (64+64 = 128/wave
// -> 4 waves/SIMD) both permit more; the "2" hint is the only visible soft
// limiter. 3 keeps allocator budget <=170 VGPR (no spill risk at 128 used).
// NO block swizzle (R5): with dim3(24,64), XCD = x%8 -> each XCD owns 3 fixed
// B-column-panels (768KB, L2-resident). Epilogue (R9): category wave-uniform
// per j -> hoisted branch; V packed as ushort4.
template <int MODE>
__global__ __launch_bounds__(256, 3) void gemm_bt(
    const unsigned short* __restrict__ A,   // [M,K] bf16
    const unsigned short* __restrict__ Bm,  // [N,K] bf16
    const float* __restrict__ bias,         // [N] fp32
    void* __restrict__ Cv,                  // MODE0: fp32 [M,N]
    unsigned short* __restrict__ Qp,        // MODE1: [bh][s][64]
    unsigned short* __restrict__ Kp,        // MODE1: [bh][s][64]
    unsigned short* __restrict__ Vp,        // MODE1: [bh][d][s]
    int M, int N, int K) {
  __shared__ __align__(16) unsigned short As[128 * 64];
  __shared__ __align__(16) unsigned short Bs[128 * 64];
  const int tid = threadIdx.x;
  const int lane = tid & 63, wave = tid >> 6;
  const int m0 = blockIdx.y * 128, n0 = blockIdx.x * 128;
  const int wm = (wave >> 1) * 64, wn = (wave & 1) * 64;
  const int fr = lane & 15, fq = lane >> 4;

  f32x4 acc[4][4];
#pragma unroll
  for (int i = 0; i < 4; i++)
#pragma unroll
    for (int j = 0; j < 4; j++) acc[i][j] = (f32x4){0.f, 0.f, 0.f, 0.f};

  const int srow = lane >> 3;                   // 0..7 within 8-row chunk
  const int scol = ((lane & 7) ^ srow) * 8;     // swizzled global col (elems)

  for (int kt = 0; kt < K; kt += 64) {
    __syncthreads();
#pragma unroll
    for (int c = 0; c < 4; c++) {
      const int chunk = wave * 4 + c;           // 0..15, 8 rows each
      const int row = chunk * 8 + srow;
      gl_lds16(A + (size_t)(m0 + row) * K + kt + scol, As + chunk * 512);
      gl_lds16(Bm + (size_t)(n0 + row) * K + kt + scol, Bs + chunk * 512);
    }
    __syncthreads();
#pragma unroll
    for (int s = 0; s < 2; s++) {
      bf16x8 af[4], bf[4];
#pragma unroll
      for (int i = 0; i < 4; i++)
        af[i] = *(const bf16x8*)(As + (wm + i * 16 + fr) * 64 +
                                 (((s * 4 + fq) ^ (fr & 7)) * 8));
#pragma unroll
      for (int j = 0; j < 4; j++)
        bf[j] = *(const bf16x8*)(Bs + (wn + j * 16 + fr) * 64 +
                                 (((s * 4 + fq) ^ (fr & 7)) * 8));
#pragma unroll
      for (int i = 0; i < 4; i++)
#pragma unroll
        for (int j = 0; j < 4; j++)
          acc[i][j] = __builtin_amdgcn_mfma_f32_16x16x32_bf16(af[i], bf[j], acc[i][j], 0, 0, 0);
    }
  }

#pragma unroll
  for (int j = 0; j < 4; j++) {
    const int col = n0 + wn + j * 16 + fr;
    const float bval = bias[col];
    if (MODE == 0) {
#pragma unroll
      for (int i = 0; i < 4; i++)
#pragma unroll
        for (int r = 0; r < 4; r++) {
          const int row = m0 + wm + i * 16 + fq * 4 + r;
          ((float*)Cv)[(size_t)row * N + col] = acc[i][j][r] + bval;
        }
    } else {
      const int h = col / 192, rr = col - h * 192;
      if (rr < 64) {          // Q, pre-scaled into exp2 domain
#pragma unroll
        for (int i = 0; i < 4; i++)
#pragma unroll
          for (int r = 0; r < 4; r++) {
            const int row = m0 + wm + i * 16 + fq * 4 + r;
            const int b = row >> 11, s = row & 2047;
            Qp[((size_t)(b * 16 + h) * 2048 + s) * 64 + rr] =
                f2bf((acc[i][j][r] + bval) * 0.1803368802f);
          }
      } else if (rr < 128) {  // K
#pragma unroll
        for (int i = 0; i < 4; i++)
#pragma unroll
          for (int r = 0; r < 4; r++) {
            const int row = m0 + wm + i * 16 + fq * 4 + r;
            const int b = row >> 11, s = row & 2047;
            Kp[((size_t)(b * 16 + h) * 2048 + s) * 64 + (rr - 64)] =
                f2bf(acc[i][j][r] + bval);
          }
      } else {                // V transposed [d][s]: r=0..3 -> consecutive s
#pragma unroll
        for (int i = 0; i < 4; i++) {
          const int row0 = m0 + wm + i * 16 + fq * 4;   // +r stays in same b
          const int b = row0 >> 11, s = row0 & 2047;
          ushort4 o;
          o.x = f2bf(acc[i][j][0] + bval);
          o.y = f2bf(acc[i][j][1] + bval);
          o.z = f2bf(acc[i][j][2] + bval);
          o.w = f2bf(acc[i][j][3] + bval);
          *(ushort4*)(Vp + ((size_t)(b * 16 + h) * 64 + (rr - 128)) * 2048 + s) = o;
        }
      }
    }
  }
}

// ---------------- MFMA causal flash attention, S^T orientation ----------------
// R15: attn_k reverted BYTE-FOR-BYTE to the R12 version (passed, 237.4us).
// R13/R14 post-mortems: in-register P-transpose is CLOSED — R13's permlane
// direction is ambiguous (2 failures), and the correct bpermute form needs
// 32 gathers/tile (~218cy) > R12's LDS round-trip (~96cy issue + hidden
// latency) because two dest lanes pull DIFFERENT registers from the SAME
// source lane (select-before-gather is wrong; select-after doubles gathers).
// Q [bh][s][64] (scaled by log2e/8), K [bh][s][64], VT [bh][d][s].
// S^T = K x Q^T. Block = 2 waves = 64 q; q-tiles PAIRED (qt, 31-qt) -> 1024
// uniform blocks, 4 resident blocks/CU (LDS 40960B). Double-buffered K/V
// staging, prefetch-before-compute, single end-of-tile barrier.
// Ones-MFMA denominator (R7). Offset-domain softmax + lazy max-reduce (R8).
// cvt_pk_bf16 pack (R10). Per-g P-fold (R12).
__global__ __launch_bounds__(128, 2) void attn_k(
    const unsigned short* __restrict__ Qg, const unsigned short* __restrict__ Kg,
    const unsigned short* __restrict__ Vg, unsigned short* __restrict__ outa) {
  __shared__ __align__(16) unsigned short Ks[2 * 64 * 64];   // [buf][key][d] swz
  __shared__ __align__(16) unsigned short VTs[2 * 64 * 64];  // [buf][d][key] swz
  __shared__ __align__(16) unsigned short Ps[2 * 32 * 64];   // per-wave [q][key] swz
  const int tid = threadIdx.x;
  const int lane = tid & 63, wave = tid >> 6;
  const int fc = lane & 15, fq = lane >> 4, fc7 = fc & 7;
  // XCD swizzle: lin%8 = XCD -> give each XCD a contiguous 128-wg chunk (8 bh)
  const int wg = ((int)blockIdx.x & 7) * 128 + ((int)blockIdx.x >> 3);
  const int bh = wg >> 4, qx = wg & 15;
  const int b = bh >> 4, h = bh & 15;
  const int srow = lane >> 3;                   // 0..7 within 8-row chunk
  const int scol = ((lane & 7) ^ srow) * 8;     // swizzled global col (elems)
  const int pswz = fc & 14;                     // Ps 8B-block XOR swizzle
  const unsigned short* Qb = Qg + (size_t)bh * 2048 * 64;
  const unsigned short* Kb = Kg + (size_t)bh * 2048 * 64;
  const unsigned short* Vb = Vg + (size_t)bh * 64 * 2048;
  unsigned short* Pw = Ps + wave * 32 * 64;
  bf16x8 vones;                                 // bf16 1.0 x8 (A-operand)
#pragma unroll
  for (int j = 0; j < 8; j++) vones[j] = (short)0x3F80;

#pragma unroll 1
  for (int phase = 0; phase < 2; phase++) {
    const int qt = phase ? 31 - qx : qx;  // pair: 33 key-tiles total per block
    const int qw = qt * 64 + wave * 32;

    // Q B-frags: qb[g][s] = Q[qw+g*16+fc][s*32 + fq*8 + j]
    bf16x8 qb[2][2];
#pragma unroll
    for (int g = 0; g < 2; g++) {
      const unsigned short* qrow = Qb + (size_t)(qw + g * 16 + fc) * 64;
      qb[g][0] = *(const bf16x8*)(qrow + fq * 8);
      qb[g][1] = *(const bf16x8*)(qrow + 32 + fq * 8);
    }

    f32x4 O[4][2];
#pragma unroll
    for (int dt = 0; dt < 4; dt++)
#pragma unroll
      for (int g = 0; g < 2; g++) O[dt][g] = (f32x4){0.f, 0.f, 0.f, 0.f};
    f32x4 O1[2];                    // ones-row accumulator = softmax denom
#pragma unroll
    for (int g = 0; g < 2; g++) O1[g] = (f32x4){0.f, 0.f, 0.f, 0.f};
    f32x4 cz[2];                    // QK MFMA C-init = {-m}x4; m starts 0
#pragma unroll
    for (int g = 0; g < 2; g++) cz[g] = (f32x4){0.f, 0.f, 0.f, 0.f};

    // prologue: stage key-tile 0 into buffer 0
#pragma unroll
    for (int c = 0; c < 4; c++) {
      const int rbase = c * 16 + wave * 8;
      gl_lds16(Kb + (size_t)(rbase + srow) * 64 + scol, Ks + rbase * 64);
      gl_lds16(Vb + (size_t)(rbase + srow) * 2048 + scol, VTs + rbase * 64);
    }
    __syncthreads();  // implicit vmcnt(0): tile 0 resident

#pragma unroll 1
    for (int kb = 0; kb <= qt; kb++) {
      const int bsel = kb & 1;
      // prefetch tile kb+1 into the other buffer; latency hides under compute.
      if (kb < qt) {
        const size_t koff = (size_t)(kb + 1) * 4096;  // 64 rows * 64 elems
        const int voff = (kb + 1) * 64;
        unsigned short* Kd = Ks + (bsel ^ 1) * 4096;
        unsigned short* Vd = VTs + (bsel ^ 1) * 4096;
#pragma unroll
        for (int c = 0; c < 4; c++) {
          const int rbase = c * 16 + wave * 8;
          gl_lds16(Kb + koff + (size_t)(rbase + srow) * 64 + scol, Kd + rbase * 64);
          gl_lds16(Vb + (size_t)(rbase + srow) * 2048 + voff + scol, Vd + rbase * 64);
        }
      }
      const int k0 = kb * 64;
      const unsigned short* Ksb = Ks + bsel * 4096;
      const unsigned short* VTb = VTs + bsel * 4096;

      // S'^T = K x Q^T - m : row=key=k0+t*16+fq*4+r, col=q=qw+g*16+fc
      f32x4 S[4][2];
      __builtin_amdgcn_s_setprio(1);
#pragma unroll
      for (int t = 0; t < 4; t++) {
        bf16x8 ka0 = *(const bf16x8*)(Ksb + (t * 16 + fc) * 64 + ((fq ^ fc7) * 8));
        bf16x8 ka1 = *(const bf16x8*)(Ksb + (t * 16 + fc) * 64 + (((4 + fq) ^ fc7) * 8));
#pragma unroll
        for (int g = 0; g < 2; g++) {
          f32x4 s = __builtin_amdgcn_mfma_f32_16x16x32_bf16(ka0, qb[g][0], cz[g], 0, 0, 0);
          S[t][g] = __builtin_amdgcn_mfma_f32_16x16x32_bf16(ka1, qb[g][1], s, 0, 0, 0);
        }
      }
      __builtin_amdgcn_s_setprio(0);
      if (kb == qt) {  // diagonal tile: causal mask (wave-uniform branch)
#pragma unroll
        for (int t = 0; t < 4; t++)
#pragma unroll
          for (int g = 0; g < 2; g++)
#pragma unroll
            for (int r = 0; r < 4; r++)
              if (k0 + t * 16 + fq * 4 + r > qw + g * 16 + fc) S[t][g][r] = -3e38f;
      }
      // offset-domain online softmax; lazy reduce (common path: no shfl/sub).
      // Per-g fold: pack+store+load inside the g loop so g0's P LDS
      // round-trip overlaps g1's softmax VALU.
      float alpha[2] = {1.f, 1.f};
      bool resc = false;
      bf16x8 pb[2][2];
#pragma unroll
      for (int g = 0; g < 2; g++) {
        // max3-fusable tree over the 16 in-lane scores (local max only)
        float a0 = fmaxf(fmaxf(S[0][g][0], S[0][g][1]), S[0][g][2]);
        float a1 = fmaxf(fmaxf(S[0][g][3], S[1][g][0]), S[1][g][1]);
        float a2 = fmaxf(fmaxf(S[1][g][2], S[1][g][3]), S[2][g][0]);
        float a3 = fmaxf(fmaxf(S[2][g][1], S[2][g][2]), S[2][g][3]);
        float a4 = fmaxf(fmaxf(S[3][g][0], S[3][g][1]), S[3][g][2]);
        float b0 = fmaxf(fmaxf(a0, a1), a2);
        float b1 = fmaxf(fmaxf(a3, a4), S[3][g][3]);
        float cm = fmaxf(b0, b1);
        // trigger iff any q-row's tile-max exceeds m+8 (local check is
        // equivalent to reduced check under __all over the full wave)
        if (!__all(cm <= 8.0f)) {
          cm = fmaxf(cm, __shfl_xor(cm, 16, 64));   // per-q reduce (rare path)
          cm = fmaxf(cm, __shfl_xor(cm, 32, 64));
          const float delta = fmaxf(cm, 0.f);       // monotone m += delta
          alpha[g] = exp2_fast(-delta);
#pragma unroll
          for (int r = 0; r < 4; r++) cz[g][r] -= delta;
#pragma unroll
          for (int t = 0; t < 4; t++)
#pragma unroll
            for (int r = 0; r < 4; r++) S[t][g][r] -= delta;
          resc = true;
        }
#pragma unroll
        for (int t = 0; t < 4; t++)
#pragma unroll
          for (int r = 0; r < 4; r++) S[t][g][r] = exp2_fast(S[t][g][r]);
        // P pack+store for this g: 8B blocks, XOR(fc&14) swizzle
#pragma unroll
        for (int t = 0; t < 4; t++) {
          uint2 u;
          u.x = cvtpk(S[t][g][0], S[t][g][1]);
          u.y = cvtpk(S[t][g][2], S[t][g][3]);
          *(uint2*)(Pw + (g * 16 + fc) * 64 + (((t * 4 + fq) ^ pswz) * 4)) = u;
        }
        // pb load for this g (round-trip hides under next g's softmax)
        pb[g][0] = *(const bf16x8*)(Pw + (g * 16 + fc) * 64 + (((fq * 2) ^ pswz) * 4));
        pb[g][1] = *(const bf16x8*)(Pw + (g * 16 + fc) * 64 + (((8 + fq * 2) ^ pswz) * 4));
      }
      if (resc) {  // wave-uniform; rare
#pragma unroll
        for (int dt = 0; dt < 4; dt++)
#pragma unroll
          for (int g = 0; g < 2; g++)
#pragma unroll
            for (int r = 0; r < 4; r++) O[dt][g][r] *= alpha[g];
#pragma unroll
        for (int g = 0; g < 2; g++)
#pragma unroll
          for (int r = 0; r < 4; r++) O1[g][r] *= alpha[g];
      }
      // O^T += V^T x P ; denom row via ones-MFMA (full 64-key sum per lane)
      __builtin_amdgcn_s_setprio(1);
#pragma unroll
      for (int dt = 0; dt < 4; dt++) {
        bf16x8 va0 = *(const bf16x8*)(VTb + (dt * 16 + fc) * 64 + ((fq ^ fc7) * 8));
        bf16x8 va1 = *(const bf16x8*)(VTb + (dt * 16 + fc) * 64 + (((4 + fq) ^ fc7) * 8));
#pragma unroll
        for (int g = 0; g < 2; g++) {
          O[dt][g] = __builtin_amdgcn_mfma_f32_16x16x32_bf16(va0, pb[g][0], O[dt][g], 0, 0, 0);
          O[dt][g] = __builtin_amdgcn_mfma_f32_16x16x32_bf16(va1, pb[g][1], O[dt][g], 0, 0, 0);
        }
      }
#pragma unroll
      for (int g = 0; g < 2; g++) {
        O1[g] = __builtin_amdgcn_mfma_f32_16x16x32_bf16(vones, pb[g][0], O1[g], 0, 0, 0);
        O1[g] = __builtin_amdgcn_mfma_f32_16x16x32_bf16(vones, pb[g][1], O1[g], 0, 0, 0);
      }
      __builtin_amdgcn_s_setprio(0);
      // single barrier per tile; implicit vmcnt(0)+lgkmcnt(0) drain makes the
      // prefetched tile resident and all LDS reads complete -> next stage safe
      __syncthreads();
    }

    // epilogue: denom = O1 (full sum already in every lane; no reduce needed)
    float inv[2];
#pragma unroll
    for (int g = 0; g < 2; g++) inv[g] = 1.f / O1[g][0];
#pragma unroll
    for (int dt = 0; dt < 4; dt++)
#pragma unroll
      for (int g = 0; g < 2; g++) {
        uint2 u;
        u.x = cvtpk(O[dt][g][0] * inv[g], O[dt][g][1] * inv[g]);
        u.y = cvtpk(O[dt][g][2] * inv[g], O[dt][g][3] * inv[g]);
        size_t row = (size_t)(b * NS) + qw + g * 16 + fc;
        *(uint2*)(outa + row * 1024 + h * 64 + dt * 16 + fq * 4) = u;
      }
  }
}

// ---------------- launch ----------------
// ws (bf16 elems): xb[8192*1024] | wqkv[3072*1024] | wo[1024*1024]
//                  | Q[64*2048*64] | K[64*2048*64] | VT[64*64*2048] | att[8192*1024]
extern "C" void kernel_launch(void* const* d_in, const int* in_sizes, int n_in,
                              void* d_out, int out_size, void* d_ws, size_t ws_size,
                              hipStream_t stream) {
  const float* x     = (const float*)d_in[0];
  const float* qkv_w = (const float*)d_in[1];
  const float* qkv_b = (const float*)d_in[2];
  const float* out_w = (const float*)d_in[3];
  const float* out_b = (const float*)d_in[4];

  unsigned short* xb   = (unsigned short*)d_ws;
  unsigned short* wqkv = xb + (size_t)8192 * 1024;
  unsigned short* wo   = wqkv + (size_t)3072 * 1024;
  unsigned short* Qg   = wo + (size_t)1024 * 1024;
  unsigned short* Kg   = Qg + (size_t)64 * 2048 * 64;
  unsigned short* Vg   = Kg + (size_t)64 * 2048 * 64;
  unsigned short* att  = Vg + (size_t)64 * 64 * 2048;

  cast3_k<<<12288, 256, 0, stream>>>(x, qkv_w, out_w, xb);

  gemm_bt<1><<<dim3(24, 64), 256, 0, stream>>>(xb, wqkv, qkv_b, nullptr,
                                               Qg, Kg, Vg, 8192, 3072, 1024);
  attn_k<<<dim3(1024), 128, 0, stream>>>(Qg, Kg, Vg, att);
  gemm_bt<0><<<dim3(8, 64), 256, 0, stream>>>(att, wo, out_b, d_out,
                                              nullptr, nullptr, nullptr,
                                              8192, 1024, 1024);
}